// Round 11
// baseline (359.433 us; speedup 1.0000x reference)
//
#include <hip/hip_runtime.h>

#define B_ 2
#define N_ 2048
#define C_ 256
#define H_ 8
#define HD_ 32
#define EPSf 1e-5f
#define LOG2E 1.4426950408889634f
#define THRv 8.0f

typedef __bf16   bf16x8 __attribute__((ext_vector_type(8)));
typedef float    f32x4  __attribute__((ext_vector_type(4)));
typedef _Float16 f16x4  __attribute__((ext_vector_type(4)));
typedef _Float16 f16x2  __attribute__((ext_vector_type(2)));

// ---- workspace layout (byte offsets), needs 63MB (proven available) --------
static constexpr size_t MB_ = 1024 * 1024;
static constexpr size_t OFF_FANT = 0;                    // bf16 (B,N,C)   2MB (live until fusion1)
static constexpr size_t OFF_FBT  = 2 * MB_;              // bf16 (B,N,C)   2MB (dead after proj)
static constexpr size_t OFF_QPK  = 4 * MB_;              // bf16 (B,H,N,HD) 2MB
static constexpr size_t OFF_KPK  = 6 * MB_;              // bf16 (B,H,N,HD) 2MB
static constexpr size_t OFF_VPK  = 8 * MB_;              // f16 (B,C,N)    2MB
static constexpr size_t OFF_QDT  = 10 * MB_;             // bf16 (B,N,C)   2MB
static constexpr size_t OFF_KDT  = 12 * MB_;             // bf16 (B,N,C)   2MB
static constexpr size_t OFF_QQ   = 14 * MB_;             // f32 (B,N)
static constexpr size_t OFF_KK   = 14 * MB_ + 16 * 1024; // f32 (B,N)
static constexpr size_t OFF_FSD  = 14 * MB_ + 64 * 1024; // uint (B,N,N) 32MB -> ends 46.06MB
static constexpr size_t OFF_PART  = 47 * MB_;  // f16 [path2][split4][B][N][C] = 16MB -> 47..63
static constexpr size_t OFF_STATM = 2 * MB_;   // f32 [path2][split4][B][H][N] = 1MB (overlays fbT)
static constexpr size_t OFF_STATL = 3 * MB_;   // f32 same (overlays fbT)
static constexpr size_t OFF_CSLN  = 15 * MB_;  // bf16 (B,N,C) 2MB (overlays dead fsd)
static constexpr size_t OFF_CDLN  = 17 * MB_;  // bf16 (B,N,C) 2MB (overlays dead fsd)
static constexpr size_t OFF_X1T   = 19 * MB_;  // bf16 (B,N,2C) 4MB (overlays dead fsd)
static constexpr size_t WS_NEED   = 63 * MB_;

__device__ __forceinline__ float rfl(float x){
  return __uint_as_float(__builtin_amdgcn_readfirstlane(__float_as_uint(x)));
}
__device__ __forceinline__ float fexp2(float x){ return __builtin_amdgcn_exp2f(x); }
__device__ __forceinline__ bf16x8 cvt8(const float* p){
  float4 a = *reinterpret_cast<const float4*>(p);
  float4 c = *reinterpret_cast<const float4*>(p + 4);
  bf16x8 r;
  r[0]=(__bf16)a.x; r[1]=(__bf16)a.y; r[2]=(__bf16)a.z; r[3]=(__bf16)a.w;
  r[4]=(__bf16)c.x; r[5]=(__bf16)c.y; r[6]=(__bf16)c.z; r[7]=(__bf16)c.w;
  return r;
}
__device__ __forceinline__ unsigned int packh2(float lo, float hi){
  f16x2 h; h[0] = (_Float16)lo; h[1] = (_Float16)hi;
  return __builtin_bit_cast(unsigned int, h);
}
__device__ __forceinline__ void unpackh2(unsigned int u, float& lo, float& hi){
  f16x2 h = __builtin_bit_cast(f16x2, u);
  lo = (float)h[0]; hi = (float)h[1];
}
__device__ __forceinline__ f16x4 pack4(float a, float b, float c, float d){
  auto lo = __builtin_amdgcn_cvt_pkrtz(a, b);
  auto hi = __builtin_amdgcn_cvt_pkrtz(c, d);
  unsigned long long u = (unsigned long long)__builtin_bit_cast(unsigned int, lo)
      | ((unsigned long long)__builtin_bit_cast(unsigned int, hi) << 32);
  return __builtin_bit_cast(f16x4, u);
}

// ---- prep: x<64 -> LN(featA)->fanT ; x>=64 -> featB->fbT transpose ----------
__global__ __launch_bounds__(256) void prep_kernel(const float* __restrict__ featA,
    const float* __restrict__ featB, __bf16* __restrict__ fanT, __bf16* __restrict__ fbT,
    const float* __restrict__ gam, const float* __restrict__ bet){
  int b = blockIdx.y;
  int t = threadIdx.x;
  __shared__ float sh[9536];
  if (blockIdx.x < 64){
    int n0 = blockIdx.x * 32;
    int nl = t & 31, cg = t >> 5;
    float* tile = sh;               // [256][33]
    float* red1 = sh + 8448;        // [8][32]
    float* red2 = red1 + 256;       // [8][32]
    float* mus  = red2 + 256;       // [32]
    float* rss  = mus + 32;         // [32]
    float* gsh  = rss + 32;         // [256]
    float* bsh  = gsh + 256;        // [256]
    gsh[t] = gam[t]; bsh[t] = bet[t];
    #pragma unroll
    for (int i = 0; i < 32; i++){
      int c = cg * 32 + i;
      tile[c * 33 + nl] = featA[((size_t)(b * C_ + c)) * N_ + n0 + nl];
    }
    __syncthreads();
    float s1 = 0.f, s2 = 0.f;
    #pragma unroll
    for (int i = 0; i < 32; i++){
      float v = tile[(cg * 32 + i) * 33 + nl];
      s1 += v; s2 += v * v;
    }
    red1[cg * 32 + nl] = s1; red2[cg * 32 + nl] = s2;
    __syncthreads();
    if (t < 32){
      float a = 0.f, q = 0.f;
      #pragma unroll
      for (int i = 0; i < 8; i++){ a += red1[i * 32 + t]; q += red2[i * 32 + t]; }
      float m = a / (float)C_;
      mus[t] = m; rss[t] = rsqrtf(q / (float)C_ - m * m + EPSf);
    }
    __syncthreads();
    float mu = mus[nl], rs = rss[nl];
    size_t obase = ((size_t)(b * N_ + n0 + nl)) * C_;
    #pragma unroll
    for (int i = 0; i < 32; i++){
      int c = cg * 32 + i;
      fanT[obase + c] = (__bf16)((tile[c * 33 + nl] - mu) * rs * gsh[c] + bsh[c]);
    }
  } else {
    int idx = blockIdx.x - 64;
    int n0 = (idx & 31) * 64, c0 = (idx >> 5) * 64;
    float* tile = sh;               // [64][65]
    int cl = t >> 6, nl = t & 63;
    #pragma unroll
    for (int i = 0; i < 16; i++)
      tile[(i * 4 + cl) * 65 + nl] = featB[((size_t)(b * C_ + c0 + i * 4 + cl)) * N_ + n0 + nl];
    __syncthreads();
    int nr = t >> 2, cc = (t & 3) * 16;
    alignas(16) __bf16 tmp[16];
    #pragma unroll
    for (int j = 0; j < 16; j++) tmp[j] = (__bf16)tile[(cc + j) * 65 + nr];
    size_t d = ((size_t)(b * N_ + n0 + nr)) * C_ + c0 + cc;
    *reinterpret_cast<uint4*>(&fbT[d])     = *reinterpret_cast<uint4*>(&tmp[0]);
    *reinterpret_cast<uint4*>(&fbT[d + 8]) = *reinterpret_cast<uint4*>(&tmp[8]);
  }
}

// ---- 5 projection GEMMs, bf16 MFMA -----------------------------------------
__global__ __launch_bounds__(256) void proj_mfma(const __bf16* __restrict__ fanT,
    const __bf16* __restrict__ fbT, __bf16* __restrict__ wsh,
    const float* __restrict__ qw, const float* __restrict__ qb,
    const float* __restrict__ kw, const float* __restrict__ kb,
    const float* __restrict__ vw, const float* __restrict__ vb,
    const float* __restrict__ qdw, const float* __restrict__ qdb,
    const float* __restrict__ kdw, const float* __restrict__ kdb){
  const int p = blockIdx.z % 5, b = blockIdx.z / 5;
  const int t = threadIdx.x, w = t >> 6, lane = t & 63, ln = lane & 15, g = lane >> 4;
  const float *W, *bias;
  const __bf16* X;
  __bf16* Y;
  if (p == 0)      { W = qw;  bias = qb;  X = fanT; Y = wsh + (OFF_QPK - OFF_FANT) / 2; }
  else if (p == 1) { W = kw;  bias = kb;  X = fbT;  Y = wsh + (OFF_KPK - OFF_FANT) / 2; }
  else if (p == 2) { W = vw;  bias = vb;  X = fbT;  Y = wsh + (OFF_VPK - OFF_FANT) / 2; }
  else if (p == 3) { W = qdw; bias = qdb; X = fanT; Y = wsh + (OFF_QDT - OFF_FANT) / 2; }
  else             { W = kdw; bias = kdb; X = fbT;  Y = wsh + (OFF_KDT - OFF_FANT) / 2; }

  f32x4 acc[4];
  #pragma unroll
  for (int i = 0; i < 4; i++) acc[i] = (f32x4){0.f, 0.f, 0.f, 0.f};

  if (p != 2){
    const int n0w = blockIdx.x * 64 + w * 16, o0 = blockIdx.y * 64;
    #pragma unroll
    for (int ks = 0; ks < 8; ks++){
      bf16x8 af = *reinterpret_cast<const bf16x8*>(
          &X[((size_t)(b * N_ + n0w + ln)) * C_ + ks * 32 + g * 8]);
      #pragma unroll
      for (int ot = 0; ot < 4; ot++){
        bf16x8 bf = cvt8(&W[(size_t)(o0 + ot * 16 + ln) * C_ + ks * 32 + g * 8]);
        acc[ot] = __builtin_amdgcn_mfma_f32_16x16x32_bf16(af, bf, acc[ot], 0, 0, 0);
      }
    }
    const float inv = 0.17677669529663687f * LOG2E;  // q: 1/sqrt(hd) * log2e
    #pragma unroll
    for (int ot = 0; ot < 4; ot++){
      int o = o0 + ot * 16 + ln;
      float bz = bias[o];
      #pragma unroll
      for (int r = 0; r < 4; r++){
        int n = n0w + g * 4 + r;
        float val = acc[ot][r] + bz;
        if (p == 0){
          val *= inv;
          Y[(((size_t)(b * H_ + (o >> 5))) * N_ + n) * HD_ + (o & 31)] = (__bf16)val;
        } else if (p == 1){
          Y[(((size_t)(b * H_ + (o >> 5))) * N_ + n) * HD_ + (o & 31)] = (__bf16)val;
        } else {
          Y[((size_t)(b * N_ + n)) * C_ + o] = (__bf16)val;
        }
      }
    }
  } else {
    const int o0w = blockIdx.y * 64 + w * 16, n0 = blockIdx.x * 64;
    #pragma unroll
    for (int ks = 0; ks < 8; ks++){
      bf16x8 af = cvt8(&W[(size_t)(o0w + ln) * C_ + ks * 32 + g * 8]);
      #pragma unroll
      for (int nt = 0; nt < 4; nt++){
        bf16x8 bf = *reinterpret_cast<const bf16x8*>(
            &X[((size_t)(b * N_ + n0 + nt * 16 + ln)) * C_ + ks * 32 + g * 8]);
        acc[nt] = __builtin_amdgcn_mfma_f32_16x16x32_bf16(af, bf, acc[nt], 0, 0, 0);
      }
    }
    float bz[4];
    #pragma unroll
    for (int r = 0; r < 4; r++) bz[r] = vb[o0w + g * 4 + r];
    #pragma unroll
    for (int nt = 0; nt < 4; nt++)
      #pragma unroll
      for (int r = 0; r < 4; r++){
        int o = o0w + g * 4 + r, n = n0 + nt * 16 + ln;
        size_t idx = ((size_t)(b * C_ + o)) * N_ + n;
        ((_Float16*)Y)[idx] = (_Float16)(acc[nt][r] + bz[r]);
      }
  }
}

// ---- row norms from bf16 qdT/kdT -------------------------------------------
__global__ __launch_bounds__(256) void norms_b(const __bf16* __restrict__ qdT,
    const __bf16* __restrict__ kdT, float* __restrict__ qq, float* __restrict__ kk){
  int b = blockIdx.y, n = blockIdx.x * 64 + (threadIdx.x >> 2), part = threadIdx.x & 3;
  size_t base = ((size_t)(b * N_ + n)) * C_ + part * 64;
  float s1 = 0.f, s2 = 0.f;
  #pragma unroll
  for (int i = 0; i < 8; i++){
    bf16x8 a = *reinterpret_cast<const bf16x8*>(&qdT[base + i * 8]);
    bf16x8 d = *reinterpret_cast<const bf16x8*>(&kdT[base + i * 8]);
    #pragma unroll
    for (int j = 0; j < 8; j++){
      float fa = (float)a[j]; s1 += fa * fa;
      float fd = (float)d[j]; s2 += fd * fd;
    }
  }
  s1 += __shfl_xor(s1, 1); s1 += __shfl_xor(s1, 2);
  s2 += __shfl_xor(s2, 1); s2 += __shfl_xor(s2, 2);
  if (part == 0){ qq[b * N_ + n] = s1; kk[b * N_ + n] = s2; }
}

// ---- feature-dist(*log2e) + spatial-dist -> fsd packed f16x2 (B,N,N) -------
__global__ __launch_bounds__(256) void pairdist_mfma(const __bf16* __restrict__ qdT,
    const __bf16* __restrict__ kdT, const float* __restrict__ qq,
    const float* __restrict__ kk, const float* __restrict__ xyzA,
    const float* __restrict__ xyzB, unsigned int* __restrict__ fsd){
  const int t = threadIdx.x, w = t >> 6, lane = t & 63, ln = lane & 15, g = lane >> 4;
  const int b = blockIdx.z, n0 = blockIdx.y * 64, n0w = n0 + w * 16, m0 = blockIdx.x * 64;
  __shared__ float4 xa[64], xb[64];
  __shared__ unsigned int sbl[4][16][68];

  if (t < 64){
    const float* p = &xyzA[((size_t)(b * N_ + n0 + t)) * 3];
    xa[t] = make_float4(p[0], p[1], p[2], 0.f);
  } else if (t < 128){
    const float* p = &xyzB[((size_t)(b * N_ + m0 + t - 64)) * 3];
    xb[t - 64] = make_float4(p[0], p[1], p[2], 0.f);
  }
  bf16x8 qfr[8];
  #pragma unroll
  for (int ks = 0; ks < 8; ks++)
    qfr[ks] = *reinterpret_cast<const bf16x8*>(
        &qdT[((size_t)(b * N_ + n0w + ln)) * C_ + ks * 32 + g * 8]);
  float qqv[4];
  #pragma unroll
  for (int r = 0; r < 4; r++) qqv[r] = qq[b * N_ + n0w + g * 4 + r];
  __syncthreads();
  float4 xav[4];
  #pragma unroll
  for (int r = 0; r < 4; r++) xav[r] = xa[w * 16 + g * 4 + r];

  #pragma unroll
  for (int mt = 0; mt < 4; mt++){
    f32x4 a = (f32x4){0.f, 0.f, 0.f, 0.f};
    #pragma unroll
    for (int ks = 0; ks < 8; ks++){
      bf16x8 kfr = *reinterpret_cast<const bf16x8*>(
          &kdT[((size_t)(b * N_ + m0 + mt * 16 + ln)) * C_ + ks * 32 + g * 8]);
      a = __builtin_amdgcn_mfma_f32_16x16x32_bf16(qfr[ks], kfr, a, 0, 0, 0);
    }
    float kkv = kk[b * N_ + m0 + mt * 16 + ln];
    float4 xbv = xb[mt * 16 + ln];
    #pragma unroll
    for (int r = 0; r < 4; r++){
      float d2 = qqv[r] + kkv - 2.f * a[r];
      float fd = sqrtf(fmaxf(d2, 0.f)) * LOG2E;   // store in log2 domain
      float dx = xav[r].x - xbv.x, dy = xav[r].y - xbv.y, dz = xav[r].z - xbv.z;
      float sd = sqrtf(dx * dx + dy * dy + dz * dz);
      sbl[w][g * 4 + r][mt * 16 + ln] = packh2(fd, sd);
    }
  }
  #pragma unroll
  for (int it = 0; it < 4; it++){
    int row = it * 4 + (lane >> 4), cq = lane & 15;
    uint4 v = *reinterpret_cast<const uint4*>(&sbl[w][row][cq * 4]);
    *reinterpret_cast<uint4*>(&fsd[((size_t)(b * N_ + n0w + row)) * N_ + m0 + cq * 4]) = v;
  }
}

// ---- dual-path flash attention: 2 heads/wave, m-split 4, forced occupancy --
__global__ __launch_bounds__(256, 3) void dual_attn9(
    const __bf16* __restrict__ qpk, const __bf16* __restrict__ kpk,
    const _Float16* __restrict__ vph, const unsigned int* __restrict__ fsd,
    const float* __restrict__ sbw1, const float* __restrict__ sbg, const float* __restrict__ sbb,
    const float* __restrict__ sbm, const float* __restrict__ sbv,
    const float* __restrict__ sbw2, const float* __restrict__ sbb2,
    _Float16* __restrict__ partO, float* __restrict__ statM, float* __restrict__ statL){
  const int t = threadIdx.x, w = t >> 6, lane = t & 63, ln = lane & 15, g = lane >> 4;
  const int h0 = blockIdx.y * 2, h1 = h0 + 1;
  const int b = blockIdx.z >> 2, split = blockIdx.z & 3;
  const int nbase = blockIdx.x * 64 + w * 16;
  const int n = nbase + ln;
  const int mstart = split * (N_ / 4);

  float Ac[4], Bc[4], W20[4], W21[4];
  #pragma unroll
  for (int j = 0; j < 4; j++){
    float rs = rsqrtf(sbv[j] + EPSf);
    Ac[j]  = rfl(-sbw1[j] * rs * sbg[j]);
    Bc[j]  = rfl(-sbm[j] * rs * sbg[j] + sbb[j]);
    W20[j] = rfl(sbw2[h0 * 4 + j]) * LOG2E;
    W21[j] = rfl(sbw2[h1 * 4 + j]) * LOG2E;
  }
  float C00 = rfl(sbb2[h0]) * LOG2E;
  float C01 = rfl(sbb2[h1]) * LOG2E;

  bf16x8 qf0 = *reinterpret_cast<const bf16x8*>(
      &qpk[(((size_t)(b * H_ + h0)) * N_ + n) * HD_ + g * 8]);
  bf16x8 qf1 = *reinterpret_cast<const bf16x8*>(
      &qpk[(((size_t)(b * H_ + h1)) * N_ + n) * HD_ + g * 8]);
  const unsigned int* fsdrow = &fsd[((size_t)(b * N_ + n)) * N_];
  const __bf16* kb0 = &kpk[((size_t)(b * H_ + h0)) * N_ * HD_];
  const __bf16* kb1 = &kpk[((size_t)(b * H_ + h1)) * N_ * HD_];
  const _Float16* vb0 = &vph[((size_t)(b * C_ + h0 * HD_)) * N_];
  const _Float16* vb1 = &vph[((size_t)(b * C_ + h1 * HD_)) * N_];

  f32x4 os0[2], od0[2], os1[2], od1[2];
  #pragma unroll
  for (int i = 0; i < 2; i++){
    os0[i] = (f32x4){0.f,0.f,0.f,0.f}; od0[i] = (f32x4){0.f,0.f,0.f,0.f};
    os1[i] = (f32x4){0.f,0.f,0.f,0.f}; od1[i] = (f32x4){0.f,0.f,0.f,0.f};
  }
  float ms0 = -3e38f, lps0 = 0.f, md0 = -3e38f, lpd0 = 0.f;
  float ms1 = -3e38f, lps1 = 0.f, md1 = -3e38f, lpd1 = 0.f;

  for (int i = 0; i < 4; i++){
    const int m0 = mstart + i * 128;
    // two 64-wide sub-tiles per iteration keep the loop short
    #pragma unroll
    for (int half = 0; half < 2; half++){
      const int mh = m0 + half * 64;
      uint4 fu[4];
      bf16x8 kf0[4], kf1[4];
      #pragma unroll
      for (int mt = 0; mt < 4; mt++){
        fu[mt]  = *reinterpret_cast<const uint4*>(&fsdrow[mh + mt * 16 + g * 4]);
        kf0[mt] = *reinterpret_cast<const bf16x8*>(&kb0[(size_t)(mh + mt * 16 + ln) * HD_ + g * 8]);
        kf1[mt] = *reinterpret_cast<const bf16x8*>(&kb1[(size_t)(mh + mt * 16 + ln) * HD_ + g * 8]);
      }
      f32x4 sa0[4], sa1[4];
      #pragma unroll
      for (int mt = 0; mt < 4; mt++){
        f32x4 z = (f32x4){0.f, 0.f, 0.f, 0.f};
        sa0[mt] = __builtin_amdgcn_mfma_f32_16x16x32_bf16(kf0[mt], qf0, z, 0, 0, 0);
      }
      #pragma unroll
      for (int mt = 0; mt < 4; mt++){
        f32x4 z = (f32x4){0.f, 0.f, 0.f, 0.f};
        sa1[mt] = __builtin_amdgcn_mfma_f32_16x16x32_bf16(kf1[mt], qf1, z, 0, 0, 0);
      }
      f16x4 vf0[2][4], vf1[2][4];
      #pragma unroll
      for (int mt = 0; mt < 4; mt++)
        #pragma unroll
        for (int dt = 0; dt < 2; dt++){
          vf0[dt][mt] = *reinterpret_cast<const f16x4*>(
              &vb0[(size_t)(dt * 16 + ln) * N_ + mh + mt * 16 + g * 4]);
          vf1[dt][mt] = *reinterpret_cast<const f16x4*>(
              &vb1[(size_t)(dt * 16 + ln) * N_ + mh + mt * 16 + g * 4]);
        }

      f16x4 pAs0[4], pAd0[4], pAs1[4], pAd1[4];
      float tss0 = 0.f, tsd0 = 0.f, tss1 = 0.f, tsd1 = 0.f;
      float mxs0 = -3e38f, mxd0 = -3e38f, mxs1 = -3e38f, mxd1 = -3e38f;
      #pragma unroll
      for (int mt = 0; mt < 4; mt++){
        float ps0[4], pd0[4], ps1[4], pd1[4];
        #pragma unroll
        for (int r = 0; r < 4; r++){
          unsigned int uu = (r == 0) ? fu[mt].x : (r == 1) ? fu[mt].y
                          : (r == 2) ? fu[mt].z : fu[mt].w;
          float fdl, sd;
          unpackh2(uu, fdl, sd);
          float u0 = fmaxf(fmaf(Ac[0], sd, Bc[0]), 0.f);
          float u1 = fmaxf(fmaf(Ac[1], sd, Bc[1]), 0.f);
          float u2 = fmaxf(fmaf(Ac[2], sd, Bc[2]), 0.f);
          float u3 = fmaxf(fmaf(Ac[3], sd, Bc[3]), 0.f);
          float b0 = fmaf(W20[0], u0, fmaf(W20[1], u1, fmaf(W20[2], u2, fmaf(W20[3], u3, C00))));
          float b1 = fmaf(W21[0], u0, fmaf(W21[1], u1, fmaf(W21[2], u2, fmaf(W21[3], u3, C01))));
          float s0 = sa0[mt][r] + b0, d0 = fdl + b0;
          float s1 = sa1[mt][r] + b1, d1 = fdl + b1;
          mxs0 = fmaxf(mxs0, s0); mxd0 = fmaxf(mxd0, d0);
          mxs1 = fmaxf(mxs1, s1); mxd1 = fmaxf(mxd1, d1);
          ps0[r] = fexp2(s0 - ms0); pd0[r] = fexp2(d0 - md0);
          ps1[r] = fexp2(s1 - ms1); pd1[r] = fexp2(d1 - md1);
          tss0 += ps0[r]; tsd0 += pd0[r]; tss1 += ps1[r]; tsd1 += pd1[r];
        }
        pAs0[mt] = pack4(ps0[0], ps0[1], ps0[2], ps0[3]);
        pAd0[mt] = pack4(pd0[0], pd0[1], pd0[2], pd0[3]);
        pAs1[mt] = pack4(ps1[0], ps1[1], ps1[2], ps1[3]);
        pAd1[mt] = pack4(pd1[0], pd1[1], pd1[2], pd1[3]);
      }
      bool f0 = !__all(mxs0 <= ms0 + THRv);
      bool f1 = !__all(mxd0 <= md0 + THRv);
      bool f2 = !__all(mxs1 <= ms1 + THRv);
      bool f3 = !__all(mxd1 <= md1 + THRv);
      if (f0 || f1 || f2 || f3){
        if (f0){
          float mr = fmaxf(mxs0, __shfl_xor(mxs0, 16)); mr = fmaxf(mr, __shfl_xor(mr, 32));
          float nm = fmaxf(ms0, mr), f = fexp2(ms0 - nm);
          ms0 = nm; lps0 *= f;
          float a0 = __shfl(f, g*4+0), a1 = __shfl(f, g*4+1), a2 = __shfl(f, g*4+2), a3 = __shfl(f, g*4+3);
          #pragma unroll
          for (int dt = 0; dt < 2; dt++){ os0[dt][0]*=a0; os0[dt][1]*=a1; os0[dt][2]*=a2; os0[dt][3]*=a3; }
        }
        if (f1){
          float mr = fmaxf(mxd0, __shfl_xor(mxd0, 16)); mr = fmaxf(mr, __shfl_xor(mr, 32));
          float nm = fmaxf(md0, mr), f = fexp2(md0 - nm);
          md0 = nm; lpd0 *= f;
          float a0 = __shfl(f, g*4+0), a1 = __shfl(f, g*4+1), a2 = __shfl(f, g*4+2), a3 = __shfl(f, g*4+3);
          #pragma unroll
          for (int dt = 0; dt < 2; dt++){ od0[dt][0]*=a0; od0[dt][1]*=a1; od0[dt][2]*=a2; od0[dt][3]*=a3; }
        }
        if (f2){
          float mr = fmaxf(mxs1, __shfl_xor(mxs1, 16)); mr = fmaxf(mr, __shfl_xor(mr, 32));
          float nm = fmaxf(ms1, mr), f = fexp2(ms1 - nm);
          ms1 = nm; lps1 *= f;
          float a0 = __shfl(f, g*4+0), a1 = __shfl(f, g*4+1), a2 = __shfl(f, g*4+2), a3 = __shfl(f, g*4+3);
          #pragma unroll
          for (int dt = 0; dt < 2; dt++){ os1[dt][0]*=a0; os1[dt][1]*=a1; os1[dt][2]*=a2; os1[dt][3]*=a3; }
        }
        if (f3){
          float mr = fmaxf(mxd1, __shfl_xor(mxd1, 16)); mr = fmaxf(mr, __shfl_xor(mr, 32));
          float nm = fmaxf(md1, mr), f = fexp2(md1 - nm);
          md1 = nm; lpd1 *= f;
          float a0 = __shfl(f, g*4+0), a1 = __shfl(f, g*4+1), a2 = __shfl(f, g*4+2), a3 = __shfl(f, g*4+3);
          #pragma unroll
          for (int dt = 0; dt < 2; dt++){ od1[dt][0]*=a0; od1[dt][1]*=a1; od1[dt][2]*=a2; od1[dt][3]*=a3; }
        }
        tss0 = 0.f; tsd0 = 0.f; tss1 = 0.f; tsd1 = 0.f;
        #pragma unroll
        for (int mt = 0; mt < 4; mt++){
          float ps0[4], pd0[4], ps1[4], pd1[4];
          #pragma unroll
          for (int r = 0; r < 4; r++){
            unsigned int uu = (r == 0) ? fu[mt].x : (r == 1) ? fu[mt].y
                            : (r == 2) ? fu[mt].z : fu[mt].w;
            float fdl, sd;
            unpackh2(uu, fdl, sd);
            float u0 = fmaxf(fmaf(Ac[0], sd, Bc[0]), 0.f);
            float u1 = fmaxf(fmaf(Ac[1], sd, Bc[1]), 0.f);
            float u2 = fmaxf(fmaf(Ac[2], sd, Bc[2]), 0.f);
            float u3 = fmaxf(fmaf(Ac[3], sd, Bc[3]), 0.f);
            float b0 = fmaf(W20[0], u0, fmaf(W20[1], u1, fmaf(W20[2], u2, fmaf(W20[3], u3, C00))));
            float b1 = fmaf(W21[0], u0, fmaf(W21[1], u1, fmaf(W21[2], u2, fmaf(W21[3], u3, C01))));
            ps0[r] = fexp2(sa0[mt][r] + b0 - ms0); pd0[r] = fexp2(fdl + b0 - md0);
            ps1[r] = fexp2(sa1[mt][r] + b1 - ms1); pd1[r] = fexp2(fdl + b1 - md1);
            tss0 += ps0[r]; tsd0 += pd0[r]; tss1 += ps1[r]; tsd1 += pd1[r];
          }
          pAs0[mt] = pack4(ps0[0], ps0[1], ps0[2], ps0[3]);
          pAd0[mt] = pack4(pd0[0], pd0[1], pd0[2], pd0[3]);
          pAs1[mt] = pack4(ps1[0], ps1[1], ps1[2], ps1[3]);
          pAd1[mt] = pack4(pd1[0], pd1[1], pd1[2], pd1[3]);
        }
      }
      lps0 += tss0; lpd0 += tsd0; lps1 += tss1; lpd1 += tsd1;
      #pragma unroll
      for (int mt = 0; mt < 4; mt++)
        #pragma unroll
        for (int dt = 0; dt < 2; dt++){
          os0[dt] = __builtin_amdgcn_mfma_f32_16x16x16f16(pAs0[mt], vf0[dt][mt], os0[dt], 0, 0, 0);
          od0[dt] = __builtin_amdgcn_mfma_f32_16x16x16f16(pAd0[mt], vf0[dt][mt], od0[dt], 0, 0, 0);
          os1[dt] = __builtin_amdgcn_mfma_f32_16x16x16f16(pAs1[mt], vf1[dt][mt], os1[dt], 0, 0, 0);
          od1[dt] = __builtin_amdgcn_mfma_f32_16x16x16f16(pAd1[mt], vf1[dt][mt], od1[dt], 0, 0, 0);
        }
    }
  }

  // final row sums (one reduce for the whole kernel)
  lps0 += __shfl_xor(lps0, 16); lps0 += __shfl_xor(lps0, 32);
  lpd0 += __shfl_xor(lpd0, 16); lpd0 += __shfl_xor(lpd0, 32);
  lps1 += __shfl_xor(lps1, 16); lps1 += __shfl_xor(lps1, 32);
  lpd1 += __shfl_xor(lpd1, 16); lpd1 += __shfl_xor(lpd1, 32);
  float is0 = 1.f / lps0, id0 = 1.f / lpd0, is1 = 1.f / lps1, id1 = 1.f / lpd1;
  float is0r[4], id0r[4], is1r[4], id1r[4];
  #pragma unroll
  for (int r = 0; r < 4; r++){
    is0r[r] = __shfl(is0, g * 4 + r);
    id0r[r] = __shfl(id0, g * 4 + r);
    is1r[r] = __shfl(is1, g * 4 + r);
    id1r[r] = __shfl(id1, g * 4 + r);
  }
  #pragma unroll
  for (int dt = 0; dt < 2; dt++)
    #pragma unroll
    for (int r = 0; r < 4; r++){
      int nn = nbase + g * 4 + r;
      size_t rbase  = (((size_t)split * B_ + b) * N_ + nn) * C_;
      size_t rbase2 = (((size_t)(4 + split) * B_ + b) * N_ + nn) * C_;
      int ch0 = h0 * HD_ + dt * 16 + ln;
      int ch1 = h1 * HD_ + dt * 16 + ln;
      partO[rbase  + ch0] = (_Float16)(os0[dt][r] * is0r[r]);
      partO[rbase2 + ch0] = (_Float16)(od0[dt][r] * id0r[r]);
      partO[rbase  + ch1] = (_Float16)(os1[dt][r] * is1r[r]);
      partO[rbase2 + ch1] = (_Float16)(od1[dt][r] * id1r[r]);
    }
  if (lane < 16){
    int nn = nbase + lane;
    size_t s00 = (((size_t)split * B_ + b) * H_ + h0) * N_ + nn;
    size_t s10 = (((size_t)(4 + split) * B_ + b) * H_ + h0) * N_ + nn;
    size_t s01 = (((size_t)split * B_ + b) * H_ + h1) * N_ + nn;
    size_t s11 = (((size_t)(4 + split) * B_ + b) * H_ + h1) * N_ + nn;
    statM[s00] = ms0; statL[s00] = lps0;
    statM[s10] = md0; statL[s10] = lpd0;
    statM[s01] = ms1; statL[s01] = lps1;
    statM[s11] = md1; statL[s11] = lpd1;
  }
}

// ---- combine 4 m-splits + LN -> bf16 (stats in log2 domain) -----------------
__global__ __launch_bounds__(256) void combine_ln(
    const _Float16* __restrict__ partO, const float* __restrict__ statM,
    const float* __restrict__ statL, __bf16* __restrict__ csLN, __bf16* __restrict__ cdLN,
    const float* __restrict__ lsg, const float* __restrict__ lsb,
    const float* __restrict__ ldg, const float* __restrict__ ldb){
  const int path = blockIdx.y;
  const int w = threadIdx.x >> 6, lane = threadIdx.x & 63;
  const size_t row = (size_t)blockIdx.x * 4 + w;    // b*N + n
  const int b = (int)(row >> 11), n = (int)(row & (N_ - 1));
  const int h = lane >> 3;
  const float* gg = path ? ldg : lsg;
  const float* bb = path ? ldb : lsb;
  __bf16* dst = path ? cdLN : csLN;

  float m[4], l[4];
  #pragma unroll
  for (int s = 0; s < 4; s++){
    size_t si = (((size_t)(path * 4 + s) * B_ + b) * H_ + h) * N_ + n;
    m[s] = statM[si]; l[s] = statL[si];
  }
  float M = fmaxf(fmaxf(m[0], m[1]), fmaxf(m[2], m[3]));
  float wsum = 0.f;
  float o[4] = {0.f, 0.f, 0.f, 0.f};
  #pragma unroll
  for (int s = 0; s < 4; s++){
    size_t pb = (((size_t)(path * 4 + s) * B_ + b) * N_ + n) * C_ + lane * 4;
    f16x4 p = *reinterpret_cast<const f16x4*>(&partO[pb]);
    float wv = l[s] * fexp2(m[s] - M);
    wsum += wv;
    o[0] += wv * (float)p[0];
    o[1] += wv * (float)p[1];
    o[2] += wv * (float)p[2];
    o[3] += wv * (float)p[3];
  }
  float inv = 1.f / wsum;
  #pragma unroll
  for (int j = 0; j < 4; j++) o[j] *= inv;

  float s1 = o[0] + o[1] + o[2] + o[3];
  float s2 = o[0]*o[0] + o[1]*o[1] + o[2]*o[2] + o[3]*o[3];
  #pragma unroll
  for (int off = 1; off < 64; off <<= 1){
    s1 += __shfl_xor(s1, off);
    s2 += __shfl_xor(s2, off);
  }
  float mu = s1 / (float)C_;
  float rs = rsqrtf(s2 / (float)C_ - mu * mu + EPSf);
  float4 g4 = *reinterpret_cast<const float4*>(&gg[lane * 4]);
  float4 b4 = *reinterpret_cast<const float4*>(&bb[lane * 4]);
  alignas(8) __bf16 o4[4];
  o4[0] = (__bf16)((o[0] - mu) * rs * g4.x + b4.x);
  o4[1] = (__bf16)((o[1] - mu) * rs * g4.y + b4.y);
  o4[2] = (__bf16)((o[2] - mu) * rs * g4.z + b4.z);
  o4[3] = (__bf16)((o[3] - mu) * rs * g4.w + b4.w);
  *reinterpret_cast<uint2*>(&dst[row * C_ + lane * 4]) = *reinterpret_cast<uint2*>(o4);
}

// ---- fusion stage 1 ---------------------------------------------------------
__global__ __launch_bounds__(256) void fusion1_mfma(const __bf16* __restrict__ fanT,
    const __bf16* __restrict__ csLN, const __bf16* __restrict__ cdLN,
    __bf16* __restrict__ X1T, const float* __restrict__ fw1,
    const float* __restrict__ fbg, const float* __restrict__ fbb,
    const float* __restrict__ fbm, const float* __restrict__ fbv){
  const int t = threadIdx.x, w = t >> 6, lane = t & 63, ln = lane & 15, g = lane >> 4;
  const int b = blockIdx.z, o0 = blockIdx.y * 64, n0w = blockIdx.x * 64 + w * 16;
  f32x4 acc[4];
  #pragma unroll
  for (int i = 0; i < 4; i++) acc[i] = (f32x4){0.f, 0.f, 0.f, 0.f};
  const __bf16* segs[3] = {fanT, csLN, cdLN};
  #pragma unroll
  for (int ks = 0; ks < 24; ks++){
    const __bf16* base = segs[ks >> 3];
    int coff = (ks & 7) * 32 + g * 8;
    bf16x8 af = *reinterpret_cast<const bf16x8*>(
        &base[((size_t)(b * N_ + n0w + ln)) * C_ + coff]);
    #pragma unroll
    for (int ot = 0; ot < 4; ot++){
      bf16x8 bf = cvt8(&fw1[(size_t)(o0 + ot * 16 + ln) * (3 * C_) + ks * 32 + g * 8]);
      acc[ot] = __builtin_amdgcn_mfma_f32_16x16x32_bf16(af, bf, acc[ot], 0, 0, 0);
    }
  }
  #pragma unroll
  for (int ot = 0; ot < 4; ot++){
    int o = o0 + ot * 16 + ln;
    float mn = fbm[o], rs = rsqrtf(fbv[o] + EPSf), gg = fbg[o], be = fbb[o];
    #pragma unroll
    for (int r = 0; r < 4; r++){
      int n = n0w + g * 4 + r;
      float x = (acc[ot][r] - mn) * rs * gg + be;
      X1T[((size_t)(b * N_ + n)) * (2 * C_) + o] = (__bf16)fmaxf(x, 0.f);
    }
  }
}

// ---- fusion stage 2 ---------------------------------------------------------
__global__ __launch_bounds__(256) void fusion2_mfma(const __bf16* __restrict__ X1T,
    const float* __restrict__ fw2, const float* __restrict__ fb2,
    const float* __restrict__ featA, float* __restrict__ out){
  const int t = threadIdx.x, w = t >> 6, lane = t & 63, ln = lane & 15, g = lane >> 4;
  const int b = blockIdx.z, o0w = blockIdx.y * 64 + w * 16, n0 = blockIdx.x * 64;
  f32x4 acc[4];
  #pragma unroll
  for (int i = 0; i < 4; i++) acc[i] = (f32x4){0.f, 0.f, 0.f, 0.f};
  #pragma unroll
  for (int ks = 0; ks < 16; ks++){
    bf16x8 af = cvt8(&fw2[(size_t)(o0w + ln) * (2 * C_) + ks * 32 + g * 8]);
    #pragma unroll
    for (int nt = 0; nt < 4; nt++){
      bf16x8 bf = *reinterpret_cast<const bf16x8*>(
          &X1T[((size_t)(b * N_ + n0 + nt * 16 + ln)) * (2 * C_) + ks * 32 + g * 8]);
      acc[nt] = __builtin_amdgcn_mfma_f32_16x16x32_bf16(af, bf, acc[nt], 0, 0, 0);
    }
  }
  float bz[4];
  #pragma unroll
  for (int r = 0; r < 4; r++) bz[r] = fb2[o0w + g * 4 + r];
  #pragma unroll
  for (int nt = 0; nt < 4; nt++)
    #pragma unroll
    for (int r = 0; r < 4; r++){
      int o = o0w + g * 4 + r, n = n0 + nt * 16 + ln;
      size_t oi = ((size_t)(b * C_ + o)) * N_ + n;
      out[oi] = acc[nt][r] + bz[r] + featA[oi];
    }
}

extern "C" void kernel_launch(void* const* d_in, const int* in_sizes, int n_in,
                              void* d_out, int out_size, void* d_ws, size_t ws_size,
                              hipStream_t stream){
  (void)in_sizes; (void)n_in; (void)out_size;
  if (ws_size < WS_NEED) return;

  const float* xyzA  = (const float*)d_in[0];
  const float* featA = (const float*)d_in[1];
  const float* xyzB  = (const float*)d_in[2];
  const float* featB = (const float*)d_in[3];
  const float* qw  = (const float*)d_in[4];   const float* qb  = (const float*)d_in[5];
  const float* kw  = (const float*)d_in[6];   const float* kb  = (const float*)d_in[7];
  const float* vw  = (const float*)d_in[8];   const float* vb  = (const float*)d_in[9];
  const float* sbw1= (const float*)d_in[10];  const float* sbg = (const float*)d_in[11];
  const float* sbb = (const float*)d_in[12];  const float* sbm = (const float*)d_in[13];
  const float* sbv = (const float*)d_in[14];  const float* sbw2= (const float*)d_in[15];
  const float* sbb2= (const float*)d_in[16];
  const float* qdw = (const float*)d_in[17];  const float* qdb = (const float*)d_in[18];
  const float* kdw = (const float*)d_in[19];  const float* kdb = (const float*)d_in[20];
  const float* ling= (const float*)d_in[21];  const float* linb= (const float*)d_in[22];
  const float* lsg = (const float*)d_in[23];  const float* lsb = (const float*)d_in[24];
  const float* ldg = (const float*)d_in[25];  const float* ldb = (const float*)d_in[26];
  const float* fw1 = (const float*)d_in[27];  const float* fbg = (const float*)d_in[28];
  const float* fbb = (const float*)d_in[29];  const float* fbm = (const float*)d_in[30];
  const float* fbv = (const float*)d_in[31];  const float* fw2 = (const float*)d_in[32];
  const float* fb2 = (const float*)d_in[33];

  char* ws = (char*)d_ws;
  __bf16*   fanT = (__bf16*)(ws + OFF_FANT);
  __bf16*   fbT  = (__bf16*)(ws + OFF_FBT);
  __bf16*   qpk  = (__bf16*)(ws + OFF_QPK);
  __bf16*   kpk  = (__bf16*)(ws + OFF_KPK);
  _Float16* vph  = (_Float16*)(ws + OFF_VPK);
  __bf16*   qdT  = (__bf16*)(ws + OFF_QDT);
  __bf16*   kdT  = (__bf16*)(ws + OFF_KDT);
  float*    qq   = (float*)(ws + OFF_QQ);
  float*    kk   = (float*)(ws + OFF_KK);
  unsigned int* fsd = (unsigned int*)(ws + OFF_FSD);
  _Float16* partO = (_Float16*)(ws + OFF_PART);
  float*    statM = (float*)(ws + OFF_STATM);   // overlays dead fbT
  float*    statL = (float*)(ws + OFF_STATL);   // overlays dead fbT
  __bf16*   csLN  = (__bf16*)(ws + OFF_CSLN);
  __bf16*   cdLN  = (__bf16*)(ws + OFF_CDLN);
  __bf16*   X1T   = (__bf16*)(ws + OFF_X1T);
  float*    out   = (float*)d_out;

  prep_kernel<<<dim3(192, B_), 256, 0, stream>>>(featA, featB, fanT, fbT, ling, linb);
  proj_mfma<<<dim3(N_ / 64, C_ / 64, 5 * B_), 256, 0, stream>>>(
      fanT, fbT, fanT, qw, qb, kw, kb, vw, vb, qdw, qdb, kdw, kdb);
  norms_b<<<dim3(N_ / 64, B_), 256, 0, stream>>>(qdT, kdT, qq, kk);
  pairdist_mfma<<<dim3(N_ / 64, N_ / 64, B_), 256, 0, stream>>>(
      qdT, kdT, qq, kk, xyzA, xyzB, fsd);
  dual_attn9<<<dim3(N_ / 64, H_ / 2, B_ * 4), 256, 0, stream>>>(
      qpk, kpk, vph, fsd, sbw1, sbg, sbb, sbm, sbv, sbw2, sbb2,
      partO, statM, statL);
  combine_ln<<<dim3(B_ * N_ / 4, 2), 256, 0, stream>>>(
      partO, statM, statL, csLN, cdLN, lsg, lsb, ldg, ldb);
  fusion1_mfma<<<dim3(N_ / 64, (2 * C_) / 64, B_), 256, 0, stream>>>(
      fanT, csLN, cdLN, X1T, fw1, fbg, fbb, fbm, fbv);
  fusion2_mfma<<<dim3(N_ / 64, C_ / 64, B_), 256, 0, stream>>>(
      X1T, fw2, fb2, featA, out);
}

// Round 12
// 341.345 us; speedup vs baseline: 1.0530x; 1.0530x over previous
//
#include <hip/hip_runtime.h>

#define B_ 2
#define N_ 2048
#define C_ 256
#define H_ 8
#define HD_ 32
#define EPSf 1e-5f
#define LOG2E 1.4426950408889634f
#define THRv 8.0f

typedef __bf16   bf16x8 __attribute__((ext_vector_type(8)));
typedef float    f32x4  __attribute__((ext_vector_type(4)));
typedef _Float16 f16x4  __attribute__((ext_vector_type(4)));
typedef _Float16 f16x2  __attribute__((ext_vector_type(2)));

// ---- workspace layout (byte offsets), needs 63MB (proven available) --------
static constexpr size_t MB_ = 1024 * 1024;
static constexpr size_t OFF_FANT = 0;                    // bf16 (B,N,C)   2MB
static constexpr size_t OFF_FBT  = 2 * MB_;              // bf16 (B,N,C)   2MB
static constexpr size_t OFF_QPK  = 4 * MB_;              // bf16 (B,H,N,HD) 2MB (q*log2e/sqrt(hd))
static constexpr size_t OFF_KPK  = 6 * MB_;              // bf16 (B,H,N,HD) 2MB
static constexpr size_t OFF_VPK  = 8 * MB_;              // f16 (B,C,N)    2MB
static constexpr size_t OFF_QDT  = 10 * MB_;             // bf16 (B,N,C)   2MB
static constexpr size_t OFF_KDT  = 12 * MB_;             // bf16 (B,N,C)   2MB
static constexpr size_t OFF_QQ   = 14 * MB_;             // f32 (B,N)
static constexpr size_t OFF_KK   = 14 * MB_ + 16 * 1024; // f32 (B,N)
static constexpr size_t OFF_FSD  = 14 * MB_ + 64 * 1024; // uint (B,N,N) 32MB -> ends 46.06MB
static constexpr size_t OFF_PART  = 47 * MB_;  // f16 [path2][split2][B][N][C] = 8MB
static constexpr size_t OFF_STATM = 55 * MB_;  // f32 [path2][split2][B][H][N] = 1MB
static constexpr size_t OFF_STATL = 56 * MB_;  // f32 same
static constexpr size_t OFF_CSLN  = 15 * MB_;  // bf16 (B,N,C) 2MB (overlays dead fsd)
static constexpr size_t OFF_CDLN  = 17 * MB_;  // bf16 (B,N,C) 2MB (overlays dead fsd)
static constexpr size_t OFF_X1T   = 19 * MB_;  // bf16 (B,N,2C) 4MB (overlays dead fsd)
static constexpr size_t WS_NEED   = 63 * MB_;

__device__ __forceinline__ float rfl(float x){
  return __uint_as_float(__builtin_amdgcn_readfirstlane(__float_as_uint(x)));
}
__device__ __forceinline__ float fexp2(float x){ return __builtin_amdgcn_exp2f(x); }
__device__ __forceinline__ bf16x8 cvt8(const float* p){
  float4 a = *reinterpret_cast<const float4*>(p);
  float4 c = *reinterpret_cast<const float4*>(p + 4);
  bf16x8 r;
  r[0]=(__bf16)a.x; r[1]=(__bf16)a.y; r[2]=(__bf16)a.z; r[3]=(__bf16)a.w;
  r[4]=(__bf16)c.x; r[5]=(__bf16)c.y; r[6]=(__bf16)c.z; r[7]=(__bf16)c.w;
  return r;
}
__device__ __forceinline__ unsigned int packh2(float lo, float hi){
  f16x2 h; h[0] = (_Float16)lo; h[1] = (_Float16)hi;
  return __builtin_bit_cast(unsigned int, h);
}
__device__ __forceinline__ void unpackh2(unsigned int u, float& lo, float& hi){
  f16x2 h = __builtin_bit_cast(f16x2, u);
  lo = (float)h[0]; hi = (float)h[1];
}
__device__ __forceinline__ f16x4 pack4(float a, float b, float c, float d){
  auto lo = __builtin_amdgcn_cvt_pkrtz(a, b);
  auto hi = __builtin_amdgcn_cvt_pkrtz(c, d);
  unsigned long long u = (unsigned long long)__builtin_bit_cast(unsigned int, lo)
      | ((unsigned long long)__builtin_bit_cast(unsigned int, hi) << 32);
  return __builtin_bit_cast(f16x4, u);
}

// ---- prep: x<64 -> LN(featA)->fanT ; x>=64 -> featB->fbT transpose ----------
__global__ __launch_bounds__(256) void prep_kernel(const float* __restrict__ featA,
    const float* __restrict__ featB, __bf16* __restrict__ fanT, __bf16* __restrict__ fbT,
    const float* __restrict__ gam, const float* __restrict__ bet){
  int b = blockIdx.y;
  int t = threadIdx.x;
  __shared__ float sh[9536];
  if (blockIdx.x < 64){
    int n0 = blockIdx.x * 32;
    int nl = t & 31, cg = t >> 5;
    float* tile = sh;               // [256][33]
    float* red1 = sh + 8448;        // [8][32]
    float* red2 = red1 + 256;       // [8][32]
    float* mus  = red2 + 256;       // [32]
    float* rss  = mus + 32;         // [32]
    float* gsh  = rss + 32;         // [256]
    float* bsh  = gsh + 256;        // [256]
    gsh[t] = gam[t]; bsh[t] = bet[t];
    #pragma unroll
    for (int i = 0; i < 32; i++){
      int c = cg * 32 + i;
      tile[c * 33 + nl] = featA[((size_t)(b * C_ + c)) * N_ + n0 + nl];
    }
    __syncthreads();
    float s1 = 0.f, s2 = 0.f;
    #pragma unroll
    for (int i = 0; i < 32; i++){
      float v = tile[(cg * 32 + i) * 33 + nl];
      s1 += v; s2 += v * v;
    }
    red1[cg * 32 + nl] = s1; red2[cg * 32 + nl] = s2;
    __syncthreads();
    if (t < 32){
      float a = 0.f, q = 0.f;
      #pragma unroll
      for (int i = 0; i < 8; i++){ a += red1[i * 32 + t]; q += red2[i * 32 + t]; }
      float m = a / (float)C_;
      mus[t] = m; rss[t] = rsqrtf(q / (float)C_ - m * m + EPSf);
    }
    __syncthreads();
    float mu = mus[nl], rs = rss[nl];
    size_t obase = ((size_t)(b * N_ + n0 + nl)) * C_;
    #pragma unroll
    for (int i = 0; i < 32; i++){
      int c = cg * 32 + i;
      fanT[obase + c] = (__bf16)((tile[c * 33 + nl] - mu) * rs * gsh[c] + bsh[c]);
    }
  } else {
    int idx = blockIdx.x - 64;
    int n0 = (idx & 31) * 64, c0 = (idx >> 5) * 64;
    float* tile = sh;               // [64][65]
    int cl = t >> 6, nl = t & 63;
    #pragma unroll
    for (int i = 0; i < 16; i++)
      tile[(i * 4 + cl) * 65 + nl] = featB[((size_t)(b * C_ + c0 + i * 4 + cl)) * N_ + n0 + nl];
    __syncthreads();
    int nr = t >> 2, cc = (t & 3) * 16;
    alignas(16) __bf16 tmp[16];
    #pragma unroll
    for (int j = 0; j < 16; j++) tmp[j] = (__bf16)tile[(cc + j) * 65 + nr];
    size_t d = ((size_t)(b * N_ + n0 + nr)) * C_ + c0 + cc;
    *reinterpret_cast<uint4*>(&fbT[d])     = *reinterpret_cast<uint4*>(&tmp[0]);
    *reinterpret_cast<uint4*>(&fbT[d + 8]) = *reinterpret_cast<uint4*>(&tmp[8]);
  }
}

// ---- 5 projection GEMMs, bf16 MFMA -----------------------------------------
__global__ __launch_bounds__(256) void proj_mfma(const __bf16* __restrict__ fanT,
    const __bf16* __restrict__ fbT, __bf16* __restrict__ wsh,
    const float* __restrict__ qw, const float* __restrict__ qb,
    const float* __restrict__ kw, const float* __restrict__ kb,
    const float* __restrict__ vw, const float* __restrict__ vb,
    const float* __restrict__ qdw, const float* __restrict__ qdb,
    const float* __restrict__ kdw, const float* __restrict__ kdb){
  const int p = blockIdx.z % 5, b = blockIdx.z / 5;
  const int t = threadIdx.x, w = t >> 6, lane = t & 63, ln = lane & 15, g = lane >> 4;
  const float *W, *bias;
  const __bf16* X;
  __bf16* Y;
  if (p == 0)      { W = qw;  bias = qb;  X = fanT; Y = wsh + (OFF_QPK - OFF_FANT) / 2; }
  else if (p == 1) { W = kw;  bias = kb;  X = fbT;  Y = wsh + (OFF_KPK - OFF_FANT) / 2; }
  else if (p == 2) { W = vw;  bias = vb;  X = fbT;  Y = wsh + (OFF_VPK - OFF_FANT) / 2; }
  else if (p == 3) { W = qdw; bias = qdb; X = fanT; Y = wsh + (OFF_QDT - OFF_FANT) / 2; }
  else             { W = kdw; bias = kdb; X = fbT;  Y = wsh + (OFF_KDT - OFF_FANT) / 2; }

  f32x4 acc[4];
  #pragma unroll
  for (int i = 0; i < 4; i++) acc[i] = (f32x4){0.f, 0.f, 0.f, 0.f};

  if (p != 2){
    const int n0w = blockIdx.x * 64 + w * 16, o0 = blockIdx.y * 64;
    #pragma unroll
    for (int ks = 0; ks < 8; ks++){
      bf16x8 af = *reinterpret_cast<const bf16x8*>(
          &X[((size_t)(b * N_ + n0w + ln)) * C_ + ks * 32 + g * 8]);
      #pragma unroll
      for (int ot = 0; ot < 4; ot++){
        bf16x8 bf = cvt8(&W[(size_t)(o0 + ot * 16 + ln) * C_ + ks * 32 + g * 8]);
        acc[ot] = __builtin_amdgcn_mfma_f32_16x16x32_bf16(af, bf, acc[ot], 0, 0, 0);
      }
    }
    const float inv = 0.17677669529663687f * LOG2E;  // q: 1/sqrt(hd) * log2e
    #pragma unroll
    for (int ot = 0; ot < 4; ot++){
      int o = o0 + ot * 16 + ln;
      float bz = bias[o];
      #pragma unroll
      for (int r = 0; r < 4; r++){
        int n = n0w + g * 4 + r;
        float val = acc[ot][r] + bz;
        if (p == 0){
          val *= inv;
          Y[(((size_t)(b * H_ + (o >> 5))) * N_ + n) * HD_ + (o & 31)] = (__bf16)val;
        } else if (p == 1){
          Y[(((size_t)(b * H_ + (o >> 5))) * N_ + n) * HD_ + (o & 31)] = (__bf16)val;
        } else {
          Y[((size_t)(b * N_ + n)) * C_ + o] = (__bf16)val;
        }
      }
    }
  } else {
    const int o0w = blockIdx.y * 64 + w * 16, n0 = blockIdx.x * 64;
    #pragma unroll
    for (int ks = 0; ks < 8; ks++){
      bf16x8 af = cvt8(&W[(size_t)(o0w + ln) * C_ + ks * 32 + g * 8]);
      #pragma unroll
      for (int nt = 0; nt < 4; nt++){
        bf16x8 bf = *reinterpret_cast<const bf16x8*>(
            &X[((size_t)(b * N_ + n0 + nt * 16 + ln)) * C_ + ks * 32 + g * 8]);
        acc[nt] = __builtin_amdgcn_mfma_f32_16x16x32_bf16(af, bf, acc[nt], 0, 0, 0);
      }
    }
    float bz[4];
    #pragma unroll
    for (int r = 0; r < 4; r++) bz[r] = vb[o0w + g * 4 + r];
    #pragma unroll
    for (int nt = 0; nt < 4; nt++)
      #pragma unroll
      for (int r = 0; r < 4; r++){
        int o = o0w + g * 4 + r, n = n0 + nt * 16 + ln;
        size_t idx = ((size_t)(b * C_ + o)) * N_ + n;
        ((_Float16*)Y)[idx] = (_Float16)(acc[nt][r] + bz[r]);
      }
  }
}

// ---- row norms from bf16 qdT/kdT -------------------------------------------
__global__ __launch_bounds__(256) void norms_b(const __bf16* __restrict__ qdT,
    const __bf16* __restrict__ kdT, float* __restrict__ qq, float* __restrict__ kk){
  int b = blockIdx.y, n = blockIdx.x * 64 + (threadIdx.x >> 2), part = threadIdx.x & 3;
  size_t base = ((size_t)(b * N_ + n)) * C_ + part * 64;
  float s1 = 0.f, s2 = 0.f;
  #pragma unroll
  for (int i = 0; i < 8; i++){
    bf16x8 a = *reinterpret_cast<const bf16x8*>(&qdT[base + i * 8]);
    bf16x8 d = *reinterpret_cast<const bf16x8*>(&kdT[base + i * 8]);
    #pragma unroll
    for (int j = 0; j < 8; j++){
      float fa = (float)a[j]; s1 += fa * fa;
      float fd = (float)d[j]; s2 += fd * fd;
    }
  }
  s1 += __shfl_xor(s1, 1); s1 += __shfl_xor(s1, 2);
  s2 += __shfl_xor(s2, 1); s2 += __shfl_xor(s2, 2);
  if (part == 0){ qq[b * N_ + n] = s1; kk[b * N_ + n] = s2; }
}

// ---- feature-dist(*log2e) + spatial-dist -> fsd packed f16x2 (B,N,N) -------
__global__ __launch_bounds__(256) void pairdist_mfma(const __bf16* __restrict__ qdT,
    const __bf16* __restrict__ kdT, const float* __restrict__ qq,
    const float* __restrict__ kk, const float* __restrict__ xyzA,
    const float* __restrict__ xyzB, unsigned int* __restrict__ fsd){
  const int t = threadIdx.x, w = t >> 6, lane = t & 63, ln = lane & 15, g = lane >> 4;
  const int b = blockIdx.z, n0 = blockIdx.y * 64, n0w = n0 + w * 16, m0 = blockIdx.x * 64;
  __shared__ float4 xa[64], xb[64];
  __shared__ unsigned int sbl[4][16][68];

  if (t < 64){
    const float* p = &xyzA[((size_t)(b * N_ + n0 + t)) * 3];
    xa[t] = make_float4(p[0], p[1], p[2], 0.f);
  } else if (t < 128){
    const float* p = &xyzB[((size_t)(b * N_ + m0 + t - 64)) * 3];
    xb[t - 64] = make_float4(p[0], p[1], p[2], 0.f);
  }
  bf16x8 qfr[8];
  #pragma unroll
  for (int ks = 0; ks < 8; ks++)
    qfr[ks] = *reinterpret_cast<const bf16x8*>(
        &qdT[((size_t)(b * N_ + n0w + ln)) * C_ + ks * 32 + g * 8]);
  float qqv[4];
  #pragma unroll
  for (int r = 0; r < 4; r++) qqv[r] = qq[b * N_ + n0w + g * 4 + r];
  __syncthreads();
  float4 xav[4];
  #pragma unroll
  for (int r = 0; r < 4; r++) xav[r] = xa[w * 16 + g * 4 + r];

  #pragma unroll
  for (int mt = 0; mt < 4; mt++){
    f32x4 a = (f32x4){0.f, 0.f, 0.f, 0.f};
    #pragma unroll
    for (int ks = 0; ks < 8; ks++){
      bf16x8 kfr = *reinterpret_cast<const bf16x8*>(
          &kdT[((size_t)(b * N_ + m0 + mt * 16 + ln)) * C_ + ks * 32 + g * 8]);
      a = __builtin_amdgcn_mfma_f32_16x16x32_bf16(qfr[ks], kfr, a, 0, 0, 0);
    }
    float kkv = kk[b * N_ + m0 + mt * 16 + ln];
    float4 xbv = xb[mt * 16 + ln];
    #pragma unroll
    for (int r = 0; r < 4; r++){
      float d2 = qqv[r] + kkv - 2.f * a[r];
      float fd = sqrtf(fmaxf(d2, 0.f)) * LOG2E;   // store in log2 domain
      float dx = xav[r].x - xbv.x, dy = xav[r].y - xbv.y, dz = xav[r].z - xbv.z;
      float sd = sqrtf(dx * dx + dy * dy + dz * dz);
      sbl[w][g * 4 + r][mt * 16 + ln] = packh2(fd, sd);
    }
  }
  #pragma unroll
  for (int it = 0; it < 4; it++){
    int row = it * 4 + (lane >> 4), cq = lane & 15;
    uint4 v = *reinterpret_cast<const uint4*>(&sbl[w][row][cq * 4]);
    *reinterpret_cast<uint4*>(&fsd[((size_t)(b * N_ + n0w + row)) * N_ + m0 + cq * 4]) = v;
  }
}

// ---- dual-path flash attention: 2 heads/wave + fu/K prefetch double-buffer -
struct TileRegs2 { uint4 fu[4]; bf16x8 kf0[4]; bf16x8 kf1[4]; };

__device__ __forceinline__ void load_tile2(TileRegs2& T, const __bf16* kb0,
    const __bf16* kb1, const unsigned int* fsdrow, int m0, int ln, int g){
  #pragma unroll
  for (int mt = 0; mt < 4; mt++){
    T.fu[mt]  = *reinterpret_cast<const uint4*>(&fsdrow[m0 + mt * 16 + g * 4]);
    T.kf0[mt] = *reinterpret_cast<const bf16x8*>(&kb0[(size_t)(m0 + mt * 16 + ln) * HD_ + g * 8]);
    T.kf1[mt] = *reinterpret_cast<const bf16x8*>(&kb1[(size_t)(m0 + mt * 16 + ln) * HD_ + g * 8]);
  }
}

__device__ __forceinline__ void compute_tile2(const TileRegs2& T,
    const _Float16* vb0, const _Float16* vb1, int m0, int ln, int g,
    bf16x8 qf0, bf16x8 qf1,
    const float* Ac, const float* Bc, const float* W20, const float* W21,
    float C00, float C01,
    f32x4* os0, f32x4* od0, f32x4* os1, f32x4* od1,
    float& ms0, float& lps0, float& md0, float& lpd0,
    float& ms1, float& lps1, float& md1, float& lpd1){
  f32x4 sa0[4], sa1[4];
  #pragma unroll
  for (int mt = 0; mt < 4; mt++){
    f32x4 z = (f32x4){0.f, 0.f, 0.f, 0.f};
    sa0[mt] = __builtin_amdgcn_mfma_f32_16x16x32_bf16(T.kf0[mt], qf0, z, 0, 0, 0);
  }
  #pragma unroll
  for (int mt = 0; mt < 4; mt++){
    f32x4 z = (f32x4){0.f, 0.f, 0.f, 0.f};
    sa1[mt] = __builtin_amdgcn_mfma_f32_16x16x32_bf16(T.kf1[mt], qf1, z, 0, 0, 0);
  }
  f16x4 vf0[2][4], vf1[2][4];
  #pragma unroll
  for (int mt = 0; mt < 4; mt++)
    #pragma unroll
    for (int dt = 0; dt < 2; dt++){
      vf0[dt][mt] = *reinterpret_cast<const f16x4*>(
          &vb0[(size_t)(dt * 16 + ln) * N_ + m0 + mt * 16 + g * 4]);
      vf1[dt][mt] = *reinterpret_cast<const f16x4*>(
          &vb1[(size_t)(dt * 16 + ln) * N_ + m0 + mt * 16 + g * 4]);
    }

  f16x4 pAs0[4], pAd0[4], pAs1[4], pAd1[4];
  float tss0 = 0.f, tsd0 = 0.f, tss1 = 0.f, tsd1 = 0.f;
  float mxs0 = -3e38f, mxd0 = -3e38f, mxs1 = -3e38f, mxd1 = -3e38f;
  #pragma unroll
  for (int mt = 0; mt < 4; mt++){
    float ps0[4], pd0[4], ps1[4], pd1[4];
    #pragma unroll
    for (int r = 0; r < 4; r++){
      unsigned int uu = (r == 0) ? T.fu[mt].x : (r == 1) ? T.fu[mt].y
                      : (r == 2) ? T.fu[mt].z : T.fu[mt].w;
      float fdl, sd;
      unpackh2(uu, fdl, sd);
      float u0 = fmaxf(fmaf(Ac[0], sd, Bc[0]), 0.f);
      float u1 = fmaxf(fmaf(Ac[1], sd, Bc[1]), 0.f);
      float u2 = fmaxf(fmaf(Ac[2], sd, Bc[2]), 0.f);
      float u3 = fmaxf(fmaf(Ac[3], sd, Bc[3]), 0.f);
      float b0 = fmaf(W20[0], u0, fmaf(W20[1], u1, fmaf(W20[2], u2, fmaf(W20[3], u3, C00))));
      float b1 = fmaf(W21[0], u0, fmaf(W21[1], u1, fmaf(W21[2], u2, fmaf(W21[3], u3, C01))));
      float s0 = sa0[mt][r] + b0, d0 = fdl + b0;
      float s1 = sa1[mt][r] + b1, d1 = fdl + b1;
      mxs0 = fmaxf(mxs0, s0); mxd0 = fmaxf(mxd0, d0);
      mxs1 = fmaxf(mxs1, s1); mxd1 = fmaxf(mxd1, d1);
      ps0[r] = fexp2(s0 - ms0); pd0[r] = fexp2(d0 - md0);
      ps1[r] = fexp2(s1 - ms1); pd1[r] = fexp2(d1 - md1);
      tss0 += ps0[r]; tsd0 += pd0[r]; tss1 += ps1[r]; tsd1 += pd1[r];
    }
    pAs0[mt] = pack4(ps0[0], ps0[1], ps0[2], ps0[3]);
    pAd0[mt] = pack4(pd0[0], pd0[1], pd0[2], pd0[3]);
    pAs1[mt] = pack4(ps1[0], ps1[1], ps1[2], ps1[3]);
    pAd1[mt] = pack4(pd1[0], pd1[1], pd1[2], pd1[3]);
  }
  bool f0 = !__all(mxs0 <= ms0 + THRv);
  bool f1 = !__all(mxd0 <= md0 + THRv);
  bool f2 = !__all(mxs1 <= ms1 + THRv);
  bool f3 = !__all(mxd1 <= md1 + THRv);
  if (f0 || f1 || f2 || f3){
    if (f0){
      float mr = fmaxf(mxs0, __shfl_xor(mxs0, 16)); mr = fmaxf(mr, __shfl_xor(mr, 32));
      float nm = fmaxf(ms0, mr), f = fexp2(ms0 - nm);
      ms0 = nm; lps0 *= f;
      float a0 = __shfl(f, g*4+0), a1 = __shfl(f, g*4+1), a2 = __shfl(f, g*4+2), a3 = __shfl(f, g*4+3);
      #pragma unroll
      for (int dt = 0; dt < 2; dt++){ os0[dt][0]*=a0; os0[dt][1]*=a1; os0[dt][2]*=a2; os0[dt][3]*=a3; }
    }
    if (f1){
      float mr = fmaxf(mxd0, __shfl_xor(mxd0, 16)); mr = fmaxf(mr, __shfl_xor(mr, 32));
      float nm = fmaxf(md0, mr), f = fexp2(md0 - nm);
      md0 = nm; lpd0 *= f;
      float a0 = __shfl(f, g*4+0), a1 = __shfl(f, g*4+1), a2 = __shfl(f, g*4+2), a3 = __shfl(f, g*4+3);
      #pragma unroll
      for (int dt = 0; dt < 2; dt++){ od0[dt][0]*=a0; od0[dt][1]*=a1; od0[dt][2]*=a2; od0[dt][3]*=a3; }
    }
    if (f2){
      float mr = fmaxf(mxs1, __shfl_xor(mxs1, 16)); mr = fmaxf(mr, __shfl_xor(mr, 32));
      float nm = fmaxf(ms1, mr), f = fexp2(ms1 - nm);
      ms1 = nm; lps1 *= f;
      float a0 = __shfl(f, g*4+0), a1 = __shfl(f, g*4+1), a2 = __shfl(f, g*4+2), a3 = __shfl(f, g*4+3);
      #pragma unroll
      for (int dt = 0; dt < 2; dt++){ os1[dt][0]*=a0; os1[dt][1]*=a1; os1[dt][2]*=a2; os1[dt][3]*=a3; }
    }
    if (f3){
      float mr = fmaxf(mxd1, __shfl_xor(mxd1, 16)); mr = fmaxf(mr, __shfl_xor(mr, 32));
      float nm = fmaxf(md1, mr), f = fexp2(md1 - nm);
      md1 = nm; lpd1 *= f;
      float a0 = __shfl(f, g*4+0), a1 = __shfl(f, g*4+1), a2 = __shfl(f, g*4+2), a3 = __shfl(f, g*4+3);
      #pragma unroll
      for (int dt = 0; dt < 2; dt++){ od1[dt][0]*=a0; od1[dt][1]*=a1; od1[dt][2]*=a2; od1[dt][3]*=a3; }
    }
    tss0 = 0.f; tsd0 = 0.f; tss1 = 0.f; tsd1 = 0.f;
    #pragma unroll
    for (int mt = 0; mt < 4; mt++){
      float ps0[4], pd0[4], ps1[4], pd1[4];
      #pragma unroll
      for (int r = 0; r < 4; r++){
        unsigned int uu = (r == 0) ? T.fu[mt].x : (r == 1) ? T.fu[mt].y
                        : (r == 2) ? T.fu[mt].z : T.fu[mt].w;
        float fdl, sd;
        unpackh2(uu, fdl, sd);
        float u0 = fmaxf(fmaf(Ac[0], sd, Bc[0]), 0.f);
        float u1 = fmaxf(fmaf(Ac[1], sd, Bc[1]), 0.f);
        float u2 = fmaxf(fmaf(Ac[2], sd, Bc[2]), 0.f);
        float u3 = fmaxf(fmaf(Ac[3], sd, Bc[3]), 0.f);
        float b0 = fmaf(W20[0], u0, fmaf(W20[1], u1, fmaf(W20[2], u2, fmaf(W20[3], u3, C00))));
        float b1 = fmaf(W21[0], u0, fmaf(W21[1], u1, fmaf(W21[2], u2, fmaf(W21[3], u3, C01))));
        ps0[r] = fexp2(sa0[mt][r] + b0 - ms0); pd0[r] = fexp2(fdl + b0 - md0);
        ps1[r] = fexp2(sa1[mt][r] + b1 - ms1); pd1[r] = fexp2(fdl + b1 - md1);
        tss0 += ps0[r]; tsd0 += pd0[r]; tss1 += ps1[r]; tsd1 += pd1[r];
      }
      pAs0[mt] = pack4(ps0[0], ps0[1], ps0[2], ps0[3]);
      pAd0[mt] = pack4(pd0[0], pd0[1], pd0[2], pd0[3]);
      pAs1[mt] = pack4(ps1[0], ps1[1], ps1[2], ps1[3]);
      pAd1[mt] = pack4(pd1[0], pd1[1], pd1[2], pd1[3]);
    }
  }
  lps0 += tss0; lpd0 += tsd0; lps1 += tss1; lpd1 += tsd1;
  #pragma unroll
  for (int mt = 0; mt < 4; mt++)
    #pragma unroll
    for (int dt = 0; dt < 2; dt++){
      os0[dt] = __builtin_amdgcn_mfma_f32_16x16x16f16(pAs0[mt], vf0[dt][mt], os0[dt], 0, 0, 0);
      od0[dt] = __builtin_amdgcn_mfma_f32_16x16x16f16(pAd0[mt], vf0[dt][mt], od0[dt], 0, 0, 0);
      os1[dt] = __builtin_amdgcn_mfma_f32_16x16x16f16(pAs1[mt], vf1[dt][mt], os1[dt], 0, 0, 0);
      od1[dt] = __builtin_amdgcn_mfma_f32_16x16x16f16(pAd1[mt], vf1[dt][mt], od1[dt], 0, 0, 0);
    }
}

__global__ __launch_bounds__(256, 2) void dual_attnA(
    const __bf16* __restrict__ qpk, const __bf16* __restrict__ kpk,
    const _Float16* __restrict__ vph, const unsigned int* __restrict__ fsd,
    const float* __restrict__ sbw1, const float* __restrict__ sbg, const float* __restrict__ sbb,
    const float* __restrict__ sbm, const float* __restrict__ sbv,
    const float* __restrict__ sbw2, const float* __restrict__ sbb2,
    _Float16* __restrict__ partO, float* __restrict__ statM, float* __restrict__ statL){
  const int t = threadIdx.x, w = t >> 6, lane = t & 63, ln = lane & 15, g = lane >> 4;
  const int h0 = blockIdx.y * 2, h1 = h0 + 1;
  const int b = blockIdx.z >> 1, split = blockIdx.z & 1;
  const int nbase = blockIdx.x * 64 + w * 16;
  const int n = nbase + ln;
  const int mstart = split * (N_ / 2);

  float Ac[4], Bc[4], W20[4], W21[4];
  #pragma unroll
  for (int j = 0; j < 4; j++){
    float rs = rsqrtf(sbv[j] + EPSf);
    Ac[j]  = rfl(-sbw1[j] * rs * sbg[j]);
    Bc[j]  = rfl(-sbm[j] * rs * sbg[j] + sbb[j]);
    W20[j] = rfl(sbw2[h0 * 4 + j]) * LOG2E;
    W21[j] = rfl(sbw2[h1 * 4 + j]) * LOG2E;
  }
  float C00 = rfl(sbb2[h0]) * LOG2E;
  float C01 = rfl(sbb2[h1]) * LOG2E;

  bf16x8 qf0 = *reinterpret_cast<const bf16x8*>(
      &qpk[(((size_t)(b * H_ + h0)) * N_ + n) * HD_ + g * 8]);
  bf16x8 qf1 = *reinterpret_cast<const bf16x8*>(
      &qpk[(((size_t)(b * H_ + h1)) * N_ + n) * HD_ + g * 8]);
  const unsigned int* fsdrow = &fsd[((size_t)(b * N_ + n)) * N_];
  const __bf16* kb0 = &kpk[((size_t)(b * H_ + h0)) * N_ * HD_];
  const __bf16* kb1 = &kpk[((size_t)(b * H_ + h1)) * N_ * HD_];
  const _Float16* vb0 = &vph[((size_t)(b * C_ + h0 * HD_)) * N_];
  const _Float16* vb1 = &vph[((size_t)(b * C_ + h1 * HD_)) * N_];

  f32x4 os0[2], od0[2], os1[2], od1[2];
  #pragma unroll
  for (int i = 0; i < 2; i++){
    os0[i] = (f32x4){0.f,0.f,0.f,0.f}; od0[i] = (f32x4){0.f,0.f,0.f,0.f};
    os1[i] = (f32x4){0.f,0.f,0.f,0.f}; od1[i] = (f32x4){0.f,0.f,0.f,0.f};
  }
  float ms0 = -3e38f, lps0 = 0.f, md0 = -3e38f, lpd0 = 0.f;
  float ms1 = -3e38f, lps1 = 0.f, md1 = -3e38f, lpd1 = 0.f;

  TileRegs2 TA, TB;
  load_tile2(TA, kb0, kb1, fsdrow, mstart, ln, g);
  for (int i = 0; i < 16; i += 2){
    const int m0 = mstart + i * 64;
    load_tile2(TB, kb0, kb1, fsdrow, m0 + 64, ln, g);
    compute_tile2(TA, vb0, vb1, m0, ln, g, qf0, qf1, Ac, Bc, W20, W21, C00, C01,
                  os0, od0, os1, od1, ms0, lps0, md0, lpd0, ms1, lps1, md1, lpd1);
    if (i + 2 < 16) load_tile2(TA, kb0, kb1, fsdrow, m0 + 128, ln, g);
    compute_tile2(TB, vb0, vb1, m0 + 64, ln, g, qf0, qf1, Ac, Bc, W20, W21, C00, C01,
                  os0, od0, os1, od1, ms0, lps0, md0, lpd0, ms1, lps1, md1, lpd1);
  }

  // final row sums (one reduce for the whole kernel)
  lps0 += __shfl_xor(lps0, 16); lps0 += __shfl_xor(lps0, 32);
  lpd0 += __shfl_xor(lpd0, 16); lpd0 += __shfl_xor(lpd0, 32);
  lps1 += __shfl_xor(lps1, 16); lps1 += __shfl_xor(lps1, 32);
  lpd1 += __shfl_xor(lpd1, 16); lpd1 += __shfl_xor(lpd1, 32);
  float is0 = 1.f / lps0, id0 = 1.f / lpd0, is1 = 1.f / lps1, id1 = 1.f / lpd1;
  float is0r[4], id0r[4], is1r[4], id1r[4];
  #pragma unroll
  for (int r = 0; r < 4; r++){
    is0r[r] = __shfl(is0, g * 4 + r);
    id0r[r] = __shfl(id0, g * 4 + r);
    is1r[r] = __shfl(is1, g * 4 + r);
    id1r[r] = __shfl(id1, g * 4 + r);
  }
  #pragma unroll
  for (int dt = 0; dt < 2; dt++)
    #pragma unroll
    for (int r = 0; r < 4; r++){
      int nn = nbase + g * 4 + r;
      size_t rbase  = (((size_t)split * B_ + b) * N_ + nn) * C_;
      size_t rbase2 = (((size_t)(2 + split) * B_ + b) * N_ + nn) * C_;
      int ch0 = h0 * HD_ + dt * 16 + ln;
      int ch1 = h1 * HD_ + dt * 16 + ln;
      partO[rbase  + ch0] = (_Float16)(os0[dt][r] * is0r[r]);
      partO[rbase2 + ch0] = (_Float16)(od0[dt][r] * id0r[r]);
      partO[rbase  + ch1] = (_Float16)(os1[dt][r] * is1r[r]);
      partO[rbase2 + ch1] = (_Float16)(od1[dt][r] * id1r[r]);
    }
  if (lane < 16){
    int nn = nbase + lane;
    size_t s00 = (((size_t)split * B_ + b) * H_ + h0) * N_ + nn;
    size_t s10 = (((size_t)(2 + split) * B_ + b) * H_ + h0) * N_ + nn;
    size_t s01 = (((size_t)split * B_ + b) * H_ + h1) * N_ + nn;
    size_t s11 = (((size_t)(2 + split) * B_ + b) * H_ + h1) * N_ + nn;
    statM[s00] = ms0; statL[s00] = lps0;
    statM[s10] = md0; statL[s10] = lpd0;
    statM[s01] = ms1; statL[s01] = lps1;
    statM[s11] = md1; statL[s11] = lpd1;
  }
}

// ---- combine m-splits + LN -> bf16 (stats in log2 domain) -------------------
__global__ __launch_bounds__(256) void combine_ln(
    const _Float16* __restrict__ partO, const float* __restrict__ statM,
    const float* __restrict__ statL, __bf16* __restrict__ csLN, __bf16* __restrict__ cdLN,
    const float* __restrict__ lsg, const float* __restrict__ lsb,
    const float* __restrict__ ldg, const float* __restrict__ ldb){
  const int path = blockIdx.y;
  const int w = threadIdx.x >> 6, lane = threadIdx.x & 63;
  const size_t row = (size_t)blockIdx.x * 4 + w;    // b*N + n
  const int b = (int)(row >> 11), n = (int)(row & (N_ - 1));
  const int h = lane >> 3;
  const float* gg = path ? ldg : lsg;
  const float* bb = path ? ldb : lsb;
  __bf16* dst = path ? cdLN : csLN;

  size_t pb0 = (((size_t)(path * 2 + 0) * B_ + b) * N_ + n) * C_ + lane * 4;
  size_t pb1 = (((size_t)(path * 2 + 1) * B_ + b) * N_ + n) * C_ + lane * 4;
  f16x4 p0 = *reinterpret_cast<const f16x4*>(&partO[pb0]);
  f16x4 p1 = *reinterpret_cast<const f16x4*>(&partO[pb1]);
  size_t sb0 = (((size_t)(path * 2 + 0) * B_ + b) * H_ + h) * N_ + n;
  size_t sb1 = (((size_t)(path * 2 + 1) * B_ + b) * H_ + h) * N_ + n;
  float m0 = statM[sb0], l0 = statL[sb0];
  float m1 = statM[sb1], l1 = statL[sb1];
  float M = fmaxf(m0, m1);
  float w0 = l0 * fexp2(m0 - M), w1 = l1 * fexp2(m1 - M);
  float inv = 1.f / (w0 + w1);
  float o[4];
  #pragma unroll
  for (int j = 0; j < 4; j++)
    o[j] = (w0 * (float)p0[j] + w1 * (float)p1[j]) * inv;

  float s1 = o[0] + o[1] + o[2] + o[3];
  float s2 = o[0]*o[0] + o[1]*o[1] + o[2]*o[2] + o[3]*o[3];
  #pragma unroll
  for (int off = 1; off < 64; off <<= 1){
    s1 += __shfl_xor(s1, off);
    s2 += __shfl_xor(s2, off);
  }
  float mu = s1 / (float)C_;
  float rs = rsqrtf(s2 / (float)C_ - mu * mu + EPSf);
  float4 g4 = *reinterpret_cast<const float4*>(&gg[lane * 4]);
  float4 b4 = *reinterpret_cast<const float4*>(&bb[lane * 4]);
  alignas(8) __bf16 o4[4];
  o4[0] = (__bf16)((o[0] - mu) * rs * g4.x + b4.x);
  o4[1] = (__bf16)((o[1] - mu) * rs * g4.y + b4.y);
  o4[2] = (__bf16)((o[2] - mu) * rs * g4.z + b4.z);
  o4[3] = (__bf16)((o[3] - mu) * rs * g4.w + b4.w);
  *reinterpret_cast<uint2*>(&dst[row * C_ + lane * 4]) = *reinterpret_cast<uint2*>(o4);
}

// ---- fusion stage 1 ---------------------------------------------------------
__global__ __launch_bounds__(256) void fusion1_mfma(const __bf16* __restrict__ fanT,
    const __bf16* __restrict__ csLN, const __bf16* __restrict__ cdLN,
    __bf16* __restrict__ X1T, const float* __restrict__ fw1,
    const float* __restrict__ fbg, const float* __restrict__ fbb,
    const float* __restrict__ fbm, const float* __restrict__ fbv){
  const int t = threadIdx.x, w = t >> 6, lane = t & 63, ln = lane & 15, g = lane >> 4;
  const int b = blockIdx.z, o0 = blockIdx.y * 64, n0w = blockIdx.x * 64 + w * 16;
  f32x4 acc[4];
  #pragma unroll
  for (int i = 0; i < 4; i++) acc[i] = (f32x4){0.f, 0.f, 0.f, 0.f};
  const __bf16* segs[3] = {fanT, csLN, cdLN};
  #pragma unroll
  for (int ks = 0; ks < 24; ks++){
    const __bf16* base = segs[ks >> 3];
    int coff = (ks & 7) * 32 + g * 8;
    bf16x8 af = *reinterpret_cast<const bf16x8*>(
        &base[((size_t)(b * N_ + n0w + ln)) * C_ + coff]);
    #pragma unroll
    for (int ot = 0; ot < 4; ot++){
      bf16x8 bf = cvt8(&fw1[(size_t)(o0 + ot * 16 + ln) * (3 * C_) + ks * 32 + g * 8]);
      acc[ot] = __builtin_amdgcn_mfma_f32_16x16x32_bf16(af, bf, acc[ot], 0, 0, 0);
    }
  }
  #pragma unroll
  for (int ot = 0; ot < 4; ot++){
    int o = o0 + ot * 16 + ln;
    float mn = fbm[o], rs = rsqrtf(fbv[o] + EPSf), gg = fbg[o], be = fbb[o];
    #pragma unroll
    for (int r = 0; r < 4; r++){
      int n = n0w + g * 4 + r;
      float x = (acc[ot][r] - mn) * rs * gg + be;
      X1T[((size_t)(b * N_ + n)) * (2 * C_) + o] = (__bf16)fmaxf(x, 0.f);
    }
  }
}

// ---- fusion stage 2 ---------------------------------------------------------
__global__ __launch_bounds__(256) void fusion2_mfma(const __bf16* __restrict__ X1T,
    const float* __restrict__ fw2, const float* __restrict__ fb2,
    const float* __restrict__ featA, float* __restrict__ out){
  const int t = threadIdx.x, w = t >> 6, lane = t & 63, ln = lane & 15, g = lane >> 4;
  const int b = blockIdx.z, o0w = blockIdx.y * 64 + w * 16, n0 = blockIdx.x * 64;
  f32x4 acc[4];
  #pragma unroll
  for (int i = 0; i < 4; i++) acc[i] = (f32x4){0.f, 0.f, 0.f, 0.f};
  #pragma unroll
  for (int ks = 0; ks < 16; ks++){
    bf16x8 af = cvt8(&fw2[(size_t)(o0w + ln) * (2 * C_) + ks * 32 + g * 8]);
    #pragma unroll
    for (int nt = 0; nt < 4; nt++){
      bf16x8 bf = *reinterpret_cast<const bf16x8*>(
          &X1T[((size_t)(b * N_ + n0 + nt * 16 + ln)) * (2 * C_) + ks * 32 + g * 8]);
      acc[nt] = __builtin_amdgcn_mfma_f32_16x16x32_bf16(af, bf, acc[nt], 0, 0, 0);
    }
  }
  float bz[4];
  #pragma unroll
  for (int r = 0; r < 4; r++) bz[r] = fb2[o0w + g * 4 + r];
  #pragma unroll
  for (int nt = 0; nt < 4; nt++)
    #pragma unroll
    for (int r = 0; r < 4; r++){
      int o = o0w + g * 4 + r, n = n0 + nt * 16 + ln;
      size_t oi = ((size_t)(b * C_ + o)) * N_ + n;
      out[oi] = acc[nt][r] + bz[r] + featA[oi];
    }
}

extern "C" void kernel_launch(void* const* d_in, const int* in_sizes, int n_in,
                              void* d_out, int out_size, void* d_ws, size_t ws_size,
                              hipStream_t stream){
  (void)in_sizes; (void)n_in; (void)out_size;
  if (ws_size < WS_NEED) return;

  const float* xyzA  = (const float*)d_in[0];
  const float* featA = (const float*)d_in[1];
  const float* xyzB  = (const float*)d_in[2];
  const float* featB = (const float*)d_in[3];
  const float* qw  = (const float*)d_in[4];   const float* qb  = (const float*)d_in[5];
  const float* kw  = (const float*)d_in[6];   const float* kb  = (const float*)d_in[7];
  const float* vw  = (const float*)d_in[8];   const float* vb  = (const float*)d_in[9];
  const float* sbw1= (const float*)d_in[10];  const float* sbg = (const float*)d_in[11];
  const float* sbb = (const float*)d_in[12];  const float* sbm = (const float*)d_in[13];
  const float* sbv = (const float*)d_in[14];  const float* sbw2= (const float*)d_in[15];
  const float* sbb2= (const float*)d_in[16];
  const float* qdw = (const float*)d_in[17];  const float* qdb = (const float*)d_in[18];
  const float* kdw = (const float*)d_in[19];  const float* kdb = (const float*)d_in[20];
  const float* ling= (const float*)d_in[21];  const float* linb= (const float*)d_in[22];
  const float* lsg = (const float*)d_in[23];  const float* lsb = (const float*)d_in[24];
  const float* ldg = (const float*)d_in[25];  const float* ldb = (const float*)d_in[26];
  const float* fw1 = (const float*)d_in[27];  const float* fbg = (const float*)d_in[28];
  const float* fbb = (const float*)d_in[29];  const float* fbm = (const float*)d_in[30];
  const float* fbv = (const float*)d_in[31];  const float* fw2 = (const float*)d_in[32];
  const float* fb2 = (const float*)d_in[33];

  char* ws = (char*)d_ws;
  __bf16*   fanT = (__bf16*)(ws + OFF_FANT);
  __bf16*   fbT  = (__bf16*)(ws + OFF_FBT);
  __bf16*   qpk  = (__bf16*)(ws + OFF_QPK);
  __bf16*   kpk  = (__bf16*)(ws + OFF_KPK);
  _Float16* vph  = (_Float16*)(ws + OFF_VPK);
  __bf16*   qdT  = (__bf16*)(ws + OFF_QDT);
  __bf16*   kdT  = (__bf16*)(ws + OFF_KDT);
  float*    qq   = (float*)(ws + OFF_QQ);
  float*    kk   = (float*)(ws + OFF_KK);
  unsigned int* fsd = (unsigned int*)(ws + OFF_FSD);
  _Float16* partO = (_Float16*)(ws + OFF_PART);
  float*    statM = (float*)(ws + OFF_STATM);
  float*    statL = (float*)(ws + OFF_STATL);
  __bf16*   csLN  = (__bf16*)(ws + OFF_CSLN);
  __bf16*   cdLN  = (__bf16*)(ws + OFF_CDLN);
  __bf16*   X1T   = (__bf16*)(ws + OFF_X1T);
  float*    out   = (float*)d_out;

  prep_kernel<<<dim3(192, B_), 256, 0, stream>>>(featA, featB, fanT, fbT, ling, linb);
  proj_mfma<<<dim3(N_ / 64, C_ / 64, 5 * B_), 256, 0, stream>>>(
      fanT, fbT, fanT, qw, qb, kw, kb, vw, vb, qdw, qdb, kdw, kdb);
  norms_b<<<dim3(N_ / 64, B_), 256, 0, stream>>>(qdT, kdT, qq, kk);
  pairdist_mfma<<<dim3(N_ / 64, N_ / 64, B_), 256, 0, stream>>>(
      qdT, kdT, qq, kk, xyzA, xyzB, fsd);
  dual_attnA<<<dim3(N_ / 64, H_ / 2, B_ * 2), 256, 0, stream>>>(
      qpk, kpk, vph, fsd, sbw1, sbg, sbb, sbm, sbv, sbw2, sbb2,
      partO, statM, statL);
  combine_ln<<<dim3(B_ * N_ / 4, 2), 256, 0, stream>>>(
      partO, statM, statL, csLN, cdLN, lsg, lsb, ldg, ldb);
  fusion1_mfma<<<dim3(N_ / 64, (2 * C_) / 64, B_), 256, 0, stream>>>(
      fanT, csLN, cdLN, X1T, fw1, fbg, fbb, fbm, fbv);
  fusion2_mfma<<<dim3(N_ / 64, C_ / 64, B_), 256, 0, stream>>>(
      X1T, fw2, fb2, featA, out);
}

// Round 13
// 253.563 us; speedup vs baseline: 1.4175x; 1.3462x over previous
//
#include <hip/hip_runtime.h>

#define B_ 2
#define N_ 2048
#define C_ 256
#define H_ 8
#define HD_ 32
#define EPSf 1e-5f
#define LOG2E 1.4426950408889634f
#define THRv 8.0f

typedef __bf16   bf16x8 __attribute__((ext_vector_type(8)));
typedef float    f32x4  __attribute__((ext_vector_type(4)));
typedef _Float16 f16x4  __attribute__((ext_vector_type(4)));
typedef _Float16 f16x2  __attribute__((ext_vector_type(2)));

// ---- workspace layout (byte offsets), needs 63MB (proven available) --------
static constexpr size_t MB_ = 1024 * 1024;
static constexpr size_t OFF_FANT = 0;                    // bf16 (B,N,C)   2MB
static constexpr size_t OFF_FBT  = 2 * MB_;              // bf16 (B,N,C)   2MB
static constexpr size_t OFF_QPK  = 4 * MB_;              // bf16 (B,H,N,HD) 2MB (q*log2e/sqrt(hd))
static constexpr size_t OFF_KPK  = 6 * MB_;              // bf16 (B,H,N,HD) 2MB
static constexpr size_t OFF_VPK  = 8 * MB_;              // f16 (B,C,N)    2MB
static constexpr size_t OFF_QDT  = 10 * MB_;             // bf16 (B,N,C)   2MB
static constexpr size_t OFF_KDT  = 12 * MB_;             // bf16 (B,N,C)   2MB
static constexpr size_t OFF_QQ   = 14 * MB_;             // f32 (B,N)
static constexpr size_t OFF_KK   = 14 * MB_ + 16 * 1024; // f32 (B,N)
static constexpr size_t OFF_FSD  = 14 * MB_ + 64 * 1024; // uint (B,N,N) 32MB -> ends 46.06MB
static constexpr size_t OFF_PART  = 47 * MB_;  // f16 [path2][split2][B][N][C] = 8MB
static constexpr size_t OFF_STATM = 55 * MB_;  // f32 [path2][split2][B][H][N] = 1MB
static constexpr size_t OFF_STATL = 56 * MB_;  // f32 same
static constexpr size_t OFF_CSLN  = 15 * MB_;  // bf16 (B,N,C) 2MB (overlays dead fsd)
static constexpr size_t OFF_CDLN  = 17 * MB_;  // bf16 (B,N,C) 2MB (overlays dead fsd)
static constexpr size_t OFF_X1T   = 19 * MB_;  // bf16 (B,N,2C) 4MB (overlays dead fsd)
static constexpr size_t WS_NEED   = 63 * MB_;

__device__ __forceinline__ float rfl(float x){
  return __uint_as_float(__builtin_amdgcn_readfirstlane(__float_as_uint(x)));
}
__device__ __forceinline__ float fexp2(float x){ return __builtin_amdgcn_exp2f(x); }
__device__ __forceinline__ bf16x8 cvt8(const float* p){
  float4 a = *reinterpret_cast<const float4*>(p);
  float4 c = *reinterpret_cast<const float4*>(p + 4);
  bf16x8 r;
  r[0]=(__bf16)a.x; r[1]=(__bf16)a.y; r[2]=(__bf16)a.z; r[3]=(__bf16)a.w;
  r[4]=(__bf16)c.x; r[5]=(__bf16)c.y; r[6]=(__bf16)c.z; r[7]=(__bf16)c.w;
  return r;
}
__device__ __forceinline__ unsigned int packh2(float lo, float hi){
  f16x2 h; h[0] = (_Float16)lo; h[1] = (_Float16)hi;
  return __builtin_bit_cast(unsigned int, h);
}
__device__ __forceinline__ void unpackh2(unsigned int u, float& lo, float& hi){
  f16x2 h = __builtin_bit_cast(f16x2, u);
  lo = (float)h[0]; hi = (float)h[1];
}
__device__ __forceinline__ f16x4 pack4(float a, float b, float c, float d){
  auto lo = __builtin_amdgcn_cvt_pkrtz(a, b);
  auto hi = __builtin_amdgcn_cvt_pkrtz(c, d);
  unsigned long long u = (unsigned long long)__builtin_bit_cast(unsigned int, lo)
      | ((unsigned long long)__builtin_bit_cast(unsigned int, hi) << 32);
  return __builtin_bit_cast(f16x4, u);
}

// ---- prep: x<64 -> LN(featA)->fanT ; x>=64 -> featB->fbT transpose ----------
__global__ __launch_bounds__(256) void prep_kernel(const float* __restrict__ featA,
    const float* __restrict__ featB, __bf16* __restrict__ fanT, __bf16* __restrict__ fbT,
    const float* __restrict__ gam, const float* __restrict__ bet){
  int b = blockIdx.y;
  int t = threadIdx.x;
  __shared__ float sh[9536];
  if (blockIdx.x < 64){
    int n0 = blockIdx.x * 32;
    int nl = t & 31, cg = t >> 5;
    float* tile = sh;               // [256][33]
    float* red1 = sh + 8448;        // [8][32]
    float* red2 = red1 + 256;       // [8][32]
    float* mus  = red2 + 256;       // [32]
    float* rss  = mus + 32;         // [32]
    float* gsh  = rss + 32;         // [256]
    float* bsh  = gsh + 256;        // [256]
    gsh[t] = gam[t]; bsh[t] = bet[t];
    #pragma unroll
    for (int i = 0; i < 32; i++){
      int c = cg * 32 + i;
      tile[c * 33 + nl] = featA[((size_t)(b * C_ + c)) * N_ + n0 + nl];
    }
    __syncthreads();
    float s1 = 0.f, s2 = 0.f;
    #pragma unroll
    for (int i = 0; i < 32; i++){
      float v = tile[(cg * 32 + i) * 33 + nl];
      s1 += v; s2 += v * v;
    }
    red1[cg * 32 + nl] = s1; red2[cg * 32 + nl] = s2;
    __syncthreads();
    if (t < 32){
      float a = 0.f, q = 0.f;
      #pragma unroll
      for (int i = 0; i < 8; i++){ a += red1[i * 32 + t]; q += red2[i * 32 + t]; }
      float m = a / (float)C_;
      mus[t] = m; rss[t] = rsqrtf(q / (float)C_ - m * m + EPSf);
    }
    __syncthreads();
    float mu = mus[nl], rs = rss[nl];
    size_t obase = ((size_t)(b * N_ + n0 + nl)) * C_;
    #pragma unroll
    for (int i = 0; i < 32; i++){
      int c = cg * 32 + i;
      fanT[obase + c] = (__bf16)((tile[c * 33 + nl] - mu) * rs * gsh[c] + bsh[c]);
    }
  } else {
    int idx = blockIdx.x - 64;
    int n0 = (idx & 31) * 64, c0 = (idx >> 5) * 64;
    float* tile = sh;               // [64][65]
    int cl = t >> 6, nl = t & 63;
    #pragma unroll
    for (int i = 0; i < 16; i++)
      tile[(i * 4 + cl) * 65 + nl] = featB[((size_t)(b * C_ + c0 + i * 4 + cl)) * N_ + n0 + nl];
    __syncthreads();
    int nr = t >> 2, cc = (t & 3) * 16;
    alignas(16) __bf16 tmp[16];
    #pragma unroll
    for (int j = 0; j < 16; j++) tmp[j] = (__bf16)tile[(cc + j) * 65 + nr];
    size_t d = ((size_t)(b * N_ + n0 + nr)) * C_ + c0 + cc;
    *reinterpret_cast<uint4*>(&fbT[d])     = *reinterpret_cast<uint4*>(&tmp[0]);
    *reinterpret_cast<uint4*>(&fbT[d + 8]) = *reinterpret_cast<uint4*>(&tmp[8]);
  }
}

// ---- 5 projection GEMMs, bf16 MFMA -----------------------------------------
__global__ __launch_bounds__(256) void proj_mfma(const __bf16* __restrict__ fanT,
    const __bf16* __restrict__ fbT, __bf16* __restrict__ wsh,
    const float* __restrict__ qw, const float* __restrict__ qb,
    const float* __restrict__ kw, const float* __restrict__ kb,
    const float* __restrict__ vw, const float* __restrict__ vb,
    const float* __restrict__ qdw, const float* __restrict__ qdb,
    const float* __restrict__ kdw, const float* __restrict__ kdb){
  const int p = blockIdx.z % 5, b = blockIdx.z / 5;
  const int t = threadIdx.x, w = t >> 6, lane = t & 63, ln = lane & 15, g = lane >> 4;
  const float *W, *bias;
  const __bf16* X;
  __bf16* Y;
  if (p == 0)      { W = qw;  bias = qb;  X = fanT; Y = wsh + (OFF_QPK - OFF_FANT) / 2; }
  else if (p == 1) { W = kw;  bias = kb;  X = fbT;  Y = wsh + (OFF_KPK - OFF_FANT) / 2; }
  else if (p == 2) { W = vw;  bias = vb;  X = fbT;  Y = wsh + (OFF_VPK - OFF_FANT) / 2; }
  else if (p == 3) { W = qdw; bias = qdb; X = fanT; Y = wsh + (OFF_QDT - OFF_FANT) / 2; }
  else             { W = kdw; bias = kdb; X = fbT;  Y = wsh + (OFF_KDT - OFF_FANT) / 2; }

  f32x4 acc[4];
  #pragma unroll
  for (int i = 0; i < 4; i++) acc[i] = (f32x4){0.f, 0.f, 0.f, 0.f};

  if (p != 2){
    const int n0w = blockIdx.x * 64 + w * 16, o0 = blockIdx.y * 64;
    #pragma unroll
    for (int ks = 0; ks < 8; ks++){
      bf16x8 af = *reinterpret_cast<const bf16x8*>(
          &X[((size_t)(b * N_ + n0w + ln)) * C_ + ks * 32 + g * 8]);
      #pragma unroll
      for (int ot = 0; ot < 4; ot++){
        bf16x8 bf = cvt8(&W[(size_t)(o0 + ot * 16 + ln) * C_ + ks * 32 + g * 8]);
        acc[ot] = __builtin_amdgcn_mfma_f32_16x16x32_bf16(af, bf, acc[ot], 0, 0, 0);
      }
    }
    const float inv = 0.17677669529663687f * LOG2E;  // q: 1/sqrt(hd) * log2e
    #pragma unroll
    for (int ot = 0; ot < 4; ot++){
      int o = o0 + ot * 16 + ln;
      float bz = bias[o];
      #pragma unroll
      for (int r = 0; r < 4; r++){
        int n = n0w + g * 4 + r;
        float val = acc[ot][r] + bz;
        if (p == 0){
          val *= inv;
          Y[(((size_t)(b * H_ + (o >> 5))) * N_ + n) * HD_ + (o & 31)] = (__bf16)val;
        } else if (p == 1){
          Y[(((size_t)(b * H_ + (o >> 5))) * N_ + n) * HD_ + (o & 31)] = (__bf16)val;
        } else {
          Y[((size_t)(b * N_ + n)) * C_ + o] = (__bf16)val;
        }
      }
    }
  } else {
    const int o0w = blockIdx.y * 64 + w * 16, n0 = blockIdx.x * 64;
    #pragma unroll
    for (int ks = 0; ks < 8; ks++){
      bf16x8 af = cvt8(&W[(size_t)(o0w + ln) * C_ + ks * 32 + g * 8]);
      #pragma unroll
      for (int nt = 0; nt < 4; nt++){
        bf16x8 bf = *reinterpret_cast<const bf16x8*>(
            &X[((size_t)(b * N_ + n0 + nt * 16 + ln)) * C_ + ks * 32 + g * 8]);
        acc[nt] = __builtin_amdgcn_mfma_f32_16x16x32_bf16(af, bf, acc[nt], 0, 0, 0);
      }
    }
    float bz[4];
    #pragma unroll
    for (int r = 0; r < 4; r++) bz[r] = vb[o0w + g * 4 + r];
    #pragma unroll
    for (int nt = 0; nt < 4; nt++)
      #pragma unroll
      for (int r = 0; r < 4; r++){
        int o = o0w + g * 4 + r, n = n0 + nt * 16 + ln;
        size_t idx = ((size_t)(b * C_ + o)) * N_ + n;
        ((_Float16*)Y)[idx] = (_Float16)(acc[nt][r] + bz[r]);
      }
  }
}

// ---- row norms from bf16 qdT/kdT -------------------------------------------
__global__ __launch_bounds__(256) void norms_b(const __bf16* __restrict__ qdT,
    const __bf16* __restrict__ kdT, float* __restrict__ qq, float* __restrict__ kk){
  int b = blockIdx.y, n = blockIdx.x * 64 + (threadIdx.x >> 2), part = threadIdx.x & 3;
  size_t base = ((size_t)(b * N_ + n)) * C_ + part * 64;
  float s1 = 0.f, s2 = 0.f;
  #pragma unroll
  for (int i = 0; i < 8; i++){
    bf16x8 a = *reinterpret_cast<const bf16x8*>(&qdT[base + i * 8]);
    bf16x8 d = *reinterpret_cast<const bf16x8*>(&kdT[base + i * 8]);
    #pragma unroll
    for (int j = 0; j < 8; j++){
      float fa = (float)a[j]; s1 += fa * fa;
      float fd = (float)d[j]; s2 += fd * fd;
    }
  }
  s1 += __shfl_xor(s1, 1); s1 += __shfl_xor(s1, 2);
  s2 += __shfl_xor(s2, 1); s2 += __shfl_xor(s2, 2);
  if (part == 0){ qq[b * N_ + n] = s1; kk[b * N_ + n] = s2; }
}

// ---- feature-dist(*log2e) + spatial-dist -> fsd packed f16x2 (B,N,N) -------
__global__ __launch_bounds__(256) void pairdist_mfma(const __bf16* __restrict__ qdT,
    const __bf16* __restrict__ kdT, const float* __restrict__ qq,
    const float* __restrict__ kk, const float* __restrict__ xyzA,
    const float* __restrict__ xyzB, unsigned int* __restrict__ fsd){
  const int t = threadIdx.x, w = t >> 6, lane = t & 63, ln = lane & 15, g = lane >> 4;
  const int b = blockIdx.z, n0 = blockIdx.y * 64, n0w = n0 + w * 16, m0 = blockIdx.x * 64;
  __shared__ float4 xa[64], xb[64];
  __shared__ unsigned int sbl[4][16][68];

  if (t < 64){
    const float* p = &xyzA[((size_t)(b * N_ + n0 + t)) * 3];
    xa[t] = make_float4(p[0], p[1], p[2], 0.f);
  } else if (t < 128){
    const float* p = &xyzB[((size_t)(b * N_ + m0 + t - 64)) * 3];
    xb[t - 64] = make_float4(p[0], p[1], p[2], 0.f);
  }
  bf16x8 qfr[8];
  #pragma unroll
  for (int ks = 0; ks < 8; ks++)
    qfr[ks] = *reinterpret_cast<const bf16x8*>(
        &qdT[((size_t)(b * N_ + n0w + ln)) * C_ + ks * 32 + g * 8]);
  float qqv[4];
  #pragma unroll
  for (int r = 0; r < 4; r++) qqv[r] = qq[b * N_ + n0w + g * 4 + r];
  __syncthreads();
  float4 xav[4];
  #pragma unroll
  for (int r = 0; r < 4; r++) xav[r] = xa[w * 16 + g * 4 + r];

  #pragma unroll
  for (int mt = 0; mt < 4; mt++){
    f32x4 a = (f32x4){0.f, 0.f, 0.f, 0.f};
    #pragma unroll
    for (int ks = 0; ks < 8; ks++){
      bf16x8 kfr = *reinterpret_cast<const bf16x8*>(
          &kdT[((size_t)(b * N_ + m0 + mt * 16 + ln)) * C_ + ks * 32 + g * 8]);
      a = __builtin_amdgcn_mfma_f32_16x16x32_bf16(qfr[ks], kfr, a, 0, 0, 0);
    }
    float kkv = kk[b * N_ + m0 + mt * 16 + ln];
    float4 xbv = xb[mt * 16 + ln];
    #pragma unroll
    for (int r = 0; r < 4; r++){
      float d2 = qqv[r] + kkv - 2.f * a[r];
      float fd = sqrtf(fmaxf(d2, 0.f)) * LOG2E;   // store in log2 domain
      float dx = xav[r].x - xbv.x, dy = xav[r].y - xbv.y, dz = xav[r].z - xbv.z;
      float sd = sqrtf(dx * dx + dy * dy + dz * dz);
      sbl[w][g * 4 + r][mt * 16 + ln] = packh2(fd, sd);
    }
  }
  #pragma unroll
  for (int it = 0; it < 4; it++){
    int row = it * 4 + (lane >> 4), cq = lane & 15;
    uint4 v = *reinterpret_cast<const uint4*>(&sbl[w][row][cq * 4]);
    *reinterpret_cast<uint4*>(&fsd[((size_t)(b * N_ + n0w + row)) * N_ + m0 + cq * 4]) = v;
  }
}

// ---- dual-path flash attention: TWO HEADS PER WAVE (u-MLP shared) ----------
__global__ __launch_bounds__(256, 2) void dual_attn8(
    const __bf16* __restrict__ qpk, const __bf16* __restrict__ kpk,
    const _Float16* __restrict__ vph, const unsigned int* __restrict__ fsd,
    const float* __restrict__ sbw1, const float* __restrict__ sbg, const float* __restrict__ sbb,
    const float* __restrict__ sbm, const float* __restrict__ sbv,
    const float* __restrict__ sbw2, const float* __restrict__ sbb2,
    _Float16* __restrict__ partO, float* __restrict__ statM, float* __restrict__ statL){
  const int t = threadIdx.x, w = t >> 6, lane = t & 63, ln = lane & 15, g = lane >> 4;
  const int h0 = blockIdx.y * 2, h1 = h0 + 1;
  const int b = blockIdx.z >> 1, split = blockIdx.z & 1;
  const int nbase = blockIdx.x * 64 + w * 16;
  const int n = nbase + ln;
  const int mstart = split * (N_ / 2);

  float Ac[4], Bc[4], W20[4], W21[4];
  #pragma unroll
  for (int j = 0; j < 4; j++){
    float rs = rsqrtf(sbv[j] + EPSf);
    Ac[j]  = rfl(-sbw1[j] * rs * sbg[j]);
    Bc[j]  = rfl(-sbm[j] * rs * sbg[j] + sbb[j]);
    W20[j] = rfl(sbw2[h0 * 4 + j]) * LOG2E;
    W21[j] = rfl(sbw2[h1 * 4 + j]) * LOG2E;
  }
  float C00 = rfl(sbb2[h0]) * LOG2E;
  float C01 = rfl(sbb2[h1]) * LOG2E;

  bf16x8 qf0 = *reinterpret_cast<const bf16x8*>(
      &qpk[(((size_t)(b * H_ + h0)) * N_ + n) * HD_ + g * 8]);
  bf16x8 qf1 = *reinterpret_cast<const bf16x8*>(
      &qpk[(((size_t)(b * H_ + h1)) * N_ + n) * HD_ + g * 8]);
  const unsigned int* fsdrow = &fsd[((size_t)(b * N_ + n)) * N_];
  const __bf16* kb0 = &kpk[((size_t)(b * H_ + h0)) * N_ * HD_];
  const __bf16* kb1 = &kpk[((size_t)(b * H_ + h1)) * N_ * HD_];
  const _Float16* vb0 = &vph[((size_t)(b * C_ + h0 * HD_)) * N_];
  const _Float16* vb1 = &vph[((size_t)(b * C_ + h1 * HD_)) * N_];

  f32x4 os0[2], od0[2], os1[2], od1[2];
  #pragma unroll
  for (int i = 0; i < 2; i++){
    os0[i] = (f32x4){0.f,0.f,0.f,0.f}; od0[i] = (f32x4){0.f,0.f,0.f,0.f};
    os1[i] = (f32x4){0.f,0.f,0.f,0.f}; od1[i] = (f32x4){0.f,0.f,0.f,0.f};
  }
  float ms0 = -3e38f, lps0 = 0.f, md0 = -3e38f, lpd0 = 0.f;
  float ms1 = -3e38f, lps1 = 0.f, md1 = -3e38f, lpd1 = 0.f;

  for (int i = 0; i < 16; i++){
    const int m0 = mstart + i * 64;
    uint4 fu[4];
    bf16x8 kf0[4], kf1[4];
    #pragma unroll
    for (int mt = 0; mt < 4; mt++){
      fu[mt]  = *reinterpret_cast<const uint4*>(&fsdrow[m0 + mt * 16 + g * 4]);
      kf0[mt] = *reinterpret_cast<const bf16x8*>(&kb0[(size_t)(m0 + mt * 16 + ln) * HD_ + g * 8]);
      kf1[mt] = *reinterpret_cast<const bf16x8*>(&kb1[(size_t)(m0 + mt * 16 + ln) * HD_ + g * 8]);
    }
    f32x4 sa0[4], sa1[4];
    #pragma unroll
    for (int mt = 0; mt < 4; mt++){
      f32x4 z = (f32x4){0.f, 0.f, 0.f, 0.f};
      sa0[mt] = __builtin_amdgcn_mfma_f32_16x16x32_bf16(kf0[mt], qf0, z, 0, 0, 0);
    }
    #pragma unroll
    for (int mt = 0; mt < 4; mt++){
      f32x4 z = (f32x4){0.f, 0.f, 0.f, 0.f};
      sa1[mt] = __builtin_amdgcn_mfma_f32_16x16x32_bf16(kf1[mt], qf1, z, 0, 0, 0);
    }
    f16x4 vf0[2][4], vf1[2][4];
    #pragma unroll
    for (int mt = 0; mt < 4; mt++)
      #pragma unroll
      for (int dt = 0; dt < 2; dt++){
        vf0[dt][mt] = *reinterpret_cast<const f16x4*>(
            &vb0[(size_t)(dt * 16 + ln) * N_ + m0 + mt * 16 + g * 4]);
        vf1[dt][mt] = *reinterpret_cast<const f16x4*>(
            &vb1[(size_t)(dt * 16 + ln) * N_ + m0 + mt * 16 + g * 4]);
      }

    // shared u-MLP once per (n,m); two cheap per-head biases; speculative exp2
    f16x4 pAs0[4], pAd0[4], pAs1[4], pAd1[4];
    float tss0 = 0.f, tsd0 = 0.f, tss1 = 0.f, tsd1 = 0.f;
    float mxs0 = -3e38f, mxd0 = -3e38f, mxs1 = -3e38f, mxd1 = -3e38f;
    #pragma unroll
    for (int mt = 0; mt < 4; mt++){
      float ps0[4], pd0[4], ps1[4], pd1[4];
      #pragma unroll
      for (int r = 0; r < 4; r++){
        unsigned int uu = (r == 0) ? fu[mt].x : (r == 1) ? fu[mt].y
                        : (r == 2) ? fu[mt].z : fu[mt].w;
        float fdl, sd;
        unpackh2(uu, fdl, sd);
        float u0 = fmaxf(fmaf(Ac[0], sd, Bc[0]), 0.f);
        float u1 = fmaxf(fmaf(Ac[1], sd, Bc[1]), 0.f);
        float u2 = fmaxf(fmaf(Ac[2], sd, Bc[2]), 0.f);
        float u3 = fmaxf(fmaf(Ac[3], sd, Bc[3]), 0.f);
        float b0 = fmaf(W20[0], u0, fmaf(W20[1], u1, fmaf(W20[2], u2, fmaf(W20[3], u3, C00))));
        float b1 = fmaf(W21[0], u0, fmaf(W21[1], u1, fmaf(W21[2], u2, fmaf(W21[3], u3, C01))));
        float s0 = sa0[mt][r] + b0, d0 = fdl + b0;
        float s1 = sa1[mt][r] + b1, d1 = fdl + b1;
        mxs0 = fmaxf(mxs0, s0); mxd0 = fmaxf(mxd0, d0);
        mxs1 = fmaxf(mxs1, s1); mxd1 = fmaxf(mxd1, d1);
        ps0[r] = fexp2(s0 - ms0); pd0[r] = fexp2(d0 - md0);
        ps1[r] = fexp2(s1 - ms1); pd1[r] = fexp2(d1 - md1);
        tss0 += ps0[r]; tsd0 += pd0[r]; tss1 += ps1[r]; tsd1 += pd1[r];
      }
      pAs0[mt] = pack4(ps0[0], ps0[1], ps0[2], ps0[3]);
      pAd0[mt] = pack4(pd0[0], pd0[1], pd0[2], pd0[3]);
      pAs1[mt] = pack4(ps1[0], ps1[1], ps1[2], ps1[3]);
      pAd1[mt] = pack4(pd1[0], pd1[1], pd1[2], pd1[3]);
    }
    // defer-max votes; rare combined fixup (recompute everything)
    bool f0 = !__all(mxs0 <= ms0 + THRv);
    bool f1 = !__all(mxd0 <= md0 + THRv);
    bool f2 = !__all(mxs1 <= ms1 + THRv);
    bool f3 = !__all(mxd1 <= md1 + THRv);
    if (f0 || f1 || f2 || f3){
      if (f0){
        float mr = fmaxf(mxs0, __shfl_xor(mxs0, 16)); mr = fmaxf(mr, __shfl_xor(mr, 32));
        float nm = fmaxf(ms0, mr), f = fexp2(ms0 - nm);
        ms0 = nm; lps0 *= f;
        float a0 = __shfl(f, g*4+0), a1 = __shfl(f, g*4+1), a2 = __shfl(f, g*4+2), a3 = __shfl(f, g*4+3);
        #pragma unroll
        for (int dt = 0; dt < 2; dt++){ os0[dt][0]*=a0; os0[dt][1]*=a1; os0[dt][2]*=a2; os0[dt][3]*=a3; }
      }
      if (f1){
        float mr = fmaxf(mxd0, __shfl_xor(mxd0, 16)); mr = fmaxf(mr, __shfl_xor(mr, 32));
        float nm = fmaxf(md0, mr), f = fexp2(md0 - nm);
        md0 = nm; lpd0 *= f;
        float a0 = __shfl(f, g*4+0), a1 = __shfl(f, g*4+1), a2 = __shfl(f, g*4+2), a3 = __shfl(f, g*4+3);
        #pragma unroll
        for (int dt = 0; dt < 2; dt++){ od0[dt][0]*=a0; od0[dt][1]*=a1; od0[dt][2]*=a2; od0[dt][3]*=a3; }
      }
      if (f2){
        float mr = fmaxf(mxs1, __shfl_xor(mxs1, 16)); mr = fmaxf(mr, __shfl_xor(mr, 32));
        float nm = fmaxf(ms1, mr), f = fexp2(ms1 - nm);
        ms1 = nm; lps1 *= f;
        float a0 = __shfl(f, g*4+0), a1 = __shfl(f, g*4+1), a2 = __shfl(f, g*4+2), a3 = __shfl(f, g*4+3);
        #pragma unroll
        for (int dt = 0; dt < 2; dt++){ os1[dt][0]*=a0; os1[dt][1]*=a1; os1[dt][2]*=a2; os1[dt][3]*=a3; }
      }
      if (f3){
        float mr = fmaxf(mxd1, __shfl_xor(mxd1, 16)); mr = fmaxf(mr, __shfl_xor(mr, 32));
        float nm = fmaxf(md1, mr), f = fexp2(md1 - nm);
        md1 = nm; lpd1 *= f;
        float a0 = __shfl(f, g*4+0), a1 = __shfl(f, g*4+1), a2 = __shfl(f, g*4+2), a3 = __shfl(f, g*4+3);
        #pragma unroll
        for (int dt = 0; dt < 2; dt++){ od1[dt][0]*=a0; od1[dt][1]*=a1; od1[dt][2]*=a2; od1[dt][3]*=a3; }
      }
      tss0 = 0.f; tsd0 = 0.f; tss1 = 0.f; tsd1 = 0.f;
      #pragma unroll
      for (int mt = 0; mt < 4; mt++){
        float ps0[4], pd0[4], ps1[4], pd1[4];
        #pragma unroll
        for (int r = 0; r < 4; r++){
          unsigned int uu = (r == 0) ? fu[mt].x : (r == 1) ? fu[mt].y
                          : (r == 2) ? fu[mt].z : fu[mt].w;
          float fdl, sd;
          unpackh2(uu, fdl, sd);
          float u0 = fmaxf(fmaf(Ac[0], sd, Bc[0]), 0.f);
          float u1 = fmaxf(fmaf(Ac[1], sd, Bc[1]), 0.f);
          float u2 = fmaxf(fmaf(Ac[2], sd, Bc[2]), 0.f);
          float u3 = fmaxf(fmaf(Ac[3], sd, Bc[3]), 0.f);
          float b0 = fmaf(W20[0], u0, fmaf(W20[1], u1, fmaf(W20[2], u2, fmaf(W20[3], u3, C00))));
          float b1 = fmaf(W21[0], u0, fmaf(W21[1], u1, fmaf(W21[2], u2, fmaf(W21[3], u3, C01))));
          ps0[r] = fexp2(sa0[mt][r] + b0 - ms0); pd0[r] = fexp2(fdl + b0 - md0);
          ps1[r] = fexp2(sa1[mt][r] + b1 - ms1); pd1[r] = fexp2(fdl + b1 - md1);
          tss0 += ps0[r]; tsd0 += pd0[r]; tss1 += ps1[r]; tsd1 += pd1[r];
        }
        pAs0[mt] = pack4(ps0[0], ps0[1], ps0[2], ps0[3]);
        pAd0[mt] = pack4(pd0[0], pd0[1], pd0[2], pd0[3]);
        pAs1[mt] = pack4(ps1[0], ps1[1], ps1[2], ps1[3]);
        pAd1[mt] = pack4(pd1[0], pd1[1], pd1[2], pd1[3]);
      }
    }
    lps0 += tss0; lpd0 += tsd0; lps1 += tss1; lpd1 += tsd1;
    // PV for both heads (P already in A-fragment layout)
    #pragma unroll
    for (int mt = 0; mt < 4; mt++)
      #pragma unroll
      for (int dt = 0; dt < 2; dt++){
        os0[dt] = __builtin_amdgcn_mfma_f32_16x16x16f16(pAs0[mt], vf0[dt][mt], os0[dt], 0, 0, 0);
        od0[dt] = __builtin_amdgcn_mfma_f32_16x16x16f16(pAd0[mt], vf0[dt][mt], od0[dt], 0, 0, 0);
        os1[dt] = __builtin_amdgcn_mfma_f32_16x16x16f16(pAs1[mt], vf1[dt][mt], os1[dt], 0, 0, 0);
        od1[dt] = __builtin_amdgcn_mfma_f32_16x16x16f16(pAd1[mt], vf1[dt][mt], od1[dt], 0, 0, 0);
      }
  }

  // final row sums (one reduce for the whole kernel)
  lps0 += __shfl_xor(lps0, 16); lps0 += __shfl_xor(lps0, 32);
  lpd0 += __shfl_xor(lpd0, 16); lpd0 += __shfl_xor(lpd0, 32);
  lps1 += __shfl_xor(lps1, 16); lps1 += __shfl_xor(lps1, 32);
  lpd1 += __shfl_xor(lpd1, 16); lpd1 += __shfl_xor(lpd1, 32);
  float is0 = 1.f / lps0, id0 = 1.f / lpd0, is1 = 1.f / lps1, id1 = 1.f / lpd1;
  float is0r[4], id0r[4], is1r[4], id1r[4];
  #pragma unroll
  for (int r = 0; r < 4; r++){
    is0r[r] = __shfl(is0, g * 4 + r);
    id0r[r] = __shfl(id0, g * 4 + r);
    is1r[r] = __shfl(is1, g * 4 + r);
    id1r[r] = __shfl(id1, g * 4 + r);
  }
  #pragma unroll
  for (int dt = 0; dt < 2; dt++)
    #pragma unroll
    for (int r = 0; r < 4; r++){
      int nn = nbase + g * 4 + r;
      size_t rbase = (((size_t)split * B_ + b) * N_ + nn) * C_;
      size_t rbase2 = (((size_t)(2 + split) * B_ + b) * N_ + nn) * C_;
      int ch0 = h0 * HD_ + dt * 16 + ln;
      int ch1 = h1 * HD_ + dt * 16 + ln;
      partO[rbase  + ch0] = (_Float16)(os0[dt][r] * is0r[r]);
      partO[rbase2 + ch0] = (_Float16)(od0[dt][r] * id0r[r]);
      partO[rbase  + ch1] = (_Float16)(os1[dt][r] * is1r[r]);
      partO[rbase2 + ch1] = (_Float16)(od1[dt][r] * id1r[r]);
    }
  if (lane < 16){
    int nn = nbase + lane;
    size_t s00 = (((size_t)split * B_ + b) * H_ + h0) * N_ + nn;
    size_t s10 = (((size_t)(2 + split) * B_ + b) * H_ + h0) * N_ + nn;
    size_t s01 = (((size_t)split * B_ + b) * H_ + h1) * N_ + nn;
    size_t s11 = (((size_t)(2 + split) * B_ + b) * H_ + h1) * N_ + nn;
    statM[s00] = ms0; statL[s00] = lps0;
    statM[s10] = md0; statL[s10] = lpd0;
    statM[s01] = ms1; statL[s01] = lps1;
    statM[s11] = md1; statL[s11] = lpd1;
  }
}

// ---- combine m-splits + LN -> bf16 (stats in log2 domain) -------------------
__global__ __launch_bounds__(256) void combine_ln(
    const _Float16* __restrict__ partO, const float* __restrict__ statM,
    const float* __restrict__ statL, __bf16* __restrict__ csLN, __bf16* __restrict__ cdLN,
    const float* __restrict__ lsg, const float* __restrict__ lsb,
    const float* __restrict__ ldg, const float* __restrict__ ldb){
  const int path = blockIdx.y;
  const int w = threadIdx.x >> 6, lane = threadIdx.x & 63;
  const size_t row = (size_t)blockIdx.x * 4 + w;    // b*N + n
  const int b = (int)(row >> 11), n = (int)(row & (N_ - 1));
  const int h = lane >> 3;
  const float* gg = path ? ldg : lsg;
  const float* bb = path ? ldb : lsb;
  __bf16* dst = path ? cdLN : csLN;

  size_t pb0 = (((size_t)(path * 2 + 0) * B_ + b) * N_ + n) * C_ + lane * 4;
  size_t pb1 = (((size_t)(path * 2 + 1) * B_ + b) * N_ + n) * C_ + lane * 4;
  f16x4 p0 = *reinterpret_cast<const f16x4*>(&partO[pb0]);
  f16x4 p1 = *reinterpret_cast<const f16x4*>(&partO[pb1]);
  size_t sb0 = (((size_t)(path * 2 + 0) * B_ + b) * H_ + h) * N_ + n;
  size_t sb1 = (((size_t)(path * 2 + 1) * B_ + b) * H_ + h) * N_ + n;
  float m0 = statM[sb0], l0 = statL[sb0];
  float m1 = statM[sb1], l1 = statL[sb1];
  float M = fmaxf(m0, m1);
  float w0 = l0 * fexp2(m0 - M), w1 = l1 * fexp2(m1 - M);
  float inv = 1.f / (w0 + w1);
  float o[4];
  #pragma unroll
  for (int j = 0; j < 4; j++)
    o[j] = (w0 * (float)p0[j] + w1 * (float)p1[j]) * inv;

  float s1 = o[0] + o[1] + o[2] + o[3];
  float s2 = o[0]*o[0] + o[1]*o[1] + o[2]*o[2] + o[3]*o[3];
  #pragma unroll
  for (int off = 1; off < 64; off <<= 1){
    s1 += __shfl_xor(s1, off);
    s2 += __shfl_xor(s2, off);
  }
  float mu = s1 / (float)C_;
  float rs = rsqrtf(s2 / (float)C_ - mu * mu + EPSf);
  float4 g4 = *reinterpret_cast<const float4*>(&gg[lane * 4]);
  float4 b4 = *reinterpret_cast<const float4*>(&bb[lane * 4]);
  alignas(8) __bf16 o4[4];
  o4[0] = (__bf16)((o[0] - mu) * rs * g4.x + b4.x);
  o4[1] = (__bf16)((o[1] - mu) * rs * g4.y + b4.y);
  o4[2] = (__bf16)((o[2] - mu) * rs * g4.z + b4.z);
  o4[3] = (__bf16)((o[3] - mu) * rs * g4.w + b4.w);
  *reinterpret_cast<uint2*>(&dst[row * C_ + lane * 4]) = *reinterpret_cast<uint2*>(o4);
}

// ---- fusion stage 1 ---------------------------------------------------------
__global__ __launch_bounds__(256) void fusion1_mfma(const __bf16* __restrict__ fanT,
    const __bf16* __restrict__ csLN, const __bf16* __restrict__ cdLN,
    __bf16* __restrict__ X1T, const float* __restrict__ fw1,
    const float* __restrict__ fbg, const float* __restrict__ fbb,
    const float* __restrict__ fbm, const float* __restrict__ fbv){
  const int t = threadIdx.x, w = t >> 6, lane = t & 63, ln = lane & 15, g = lane >> 4;
  const int b = blockIdx.z, o0 = blockIdx.y * 64, n0w = blockIdx.x * 64 + w * 16;
  f32x4 acc[4];
  #pragma unroll
  for (int i = 0; i < 4; i++) acc[i] = (f32x4){0.f, 0.f, 0.f, 0.f};
  const __bf16* segs[3] = {fanT, csLN, cdLN};
  #pragma unroll
  for (int ks = 0; ks < 24; ks++){
    const __bf16* base = segs[ks >> 3];
    int coff = (ks & 7) * 32 + g * 8;
    bf16x8 af = *reinterpret_cast<const bf16x8*>(
        &base[((size_t)(b * N_ + n0w + ln)) * C_ + coff]);
    #pragma unroll
    for (int ot = 0; ot < 4; ot++){
      bf16x8 bf = cvt8(&fw1[(size_t)(o0 + ot * 16 + ln) * (3 * C_) + ks * 32 + g * 8]);
      acc[ot] = __builtin_amdgcn_mfma_f32_16x16x32_bf16(af, bf, acc[ot], 0, 0, 0);
    }
  }
  #pragma unroll
  for (int ot = 0; ot < 4; ot++){
    int o = o0 + ot * 16 + ln;
    float mn = fbm[o], rs = rsqrtf(fbv[o] + EPSf), gg = fbg[o], be = fbb[o];
    #pragma unroll
    for (int r = 0; r < 4; r++){
      int n = n0w + g * 4 + r;
      float x = (acc[ot][r] - mn) * rs * gg + be;
      X1T[((size_t)(b * N_ + n)) * (2 * C_) + o] = (__bf16)fmaxf(x, 0.f);
    }
  }
}

// ---- fusion stage 2 ---------------------------------------------------------
__global__ __launch_bounds__(256) void fusion2_mfma(const __bf16* __restrict__ X1T,
    const float* __restrict__ fw2, const float* __restrict__ fb2,
    const float* __restrict__ featA, float* __restrict__ out){
  const int t = threadIdx.x, w = t >> 6, lane = t & 63, ln = lane & 15, g = lane >> 4;
  const int b = blockIdx.z, o0w = blockIdx.y * 64 + w * 16, n0 = blockIdx.x * 64;
  f32x4 acc[4];
  #pragma unroll
  for (int i = 0; i < 4; i++) acc[i] = (f32x4){0.f, 0.f, 0.f, 0.f};
  #pragma unroll
  for (int ks = 0; ks < 16; ks++){
    bf16x8 af = cvt8(&fw2[(size_t)(o0w + ln) * (2 * C_) + ks * 32 + g * 8]);
    #pragma unroll
    for (int nt = 0; nt < 4; nt++){
      bf16x8 bf = *reinterpret_cast<const bf16x8*>(
          &X1T[((size_t)(b * N_ + n0 + nt * 16 + ln)) * (2 * C_) + ks * 32 + g * 8]);
      acc[nt] = __builtin_amdgcn_mfma_f32_16x16x32_bf16(af, bf, acc[nt], 0, 0, 0);
    }
  }
  float bz[4];
  #pragma unroll
  for (int r = 0; r < 4; r++) bz[r] = fb2[o0w + g * 4 + r];
  #pragma unroll
  for (int nt = 0; nt < 4; nt++)
    #pragma unroll
    for (int r = 0; r < 4; r++){
      int o = o0w + g * 4 + r, n = n0 + nt * 16 + ln;
      size_t oi = ((size_t)(b * C_ + o)) * N_ + n;
      out[oi] = acc[nt][r] + bz[r] + featA[oi];
    }
}

extern "C" void kernel_launch(void* const* d_in, const int* in_sizes, int n_in,
                              void* d_out, int out_size, void* d_ws, size_t ws_size,
                              hipStream_t stream){
  (void)in_sizes; (void)n_in; (void)out_size;
  if (ws_size < WS_NEED) return;

  const float* xyzA  = (const float*)d_in[0];
  const float* featA = (const float*)d_in[1];
  const float* xyzB  = (const float*)d_in[2];
  const float* featB = (const float*)d_in[3];
  const float* qw  = (const float*)d_in[4];   const float* qb  = (const float*)d_in[5];
  const float* kw  = (const float*)d_in[6];   const float* kb  = (const float*)d_in[7];
  const float* vw  = (const float*)d_in[8];   const float* vb  = (const float*)d_in[9];
  const float* sbw1= (const float*)d_in[10];  const float* sbg = (const float*)d_in[11];
  const float* sbb = (const float*)d_in[12];  const float* sbm = (const float*)d_in[13];
  const float* sbv = (const float*)d_in[14];  const float* sbw2= (const float*)d_in[15];
  const float* sbb2= (const float*)d_in[16];
  const float* qdw = (const float*)d_in[17];  const float* qdb = (const float*)d_in[18];
  const float* kdw = (const float*)d_in[19];  const float* kdb = (const float*)d_in[20];
  const float* ling= (const float*)d_in[21];  const float* linb= (const float*)d_in[22];
  const float* lsg = (const float*)d_in[23];  const float* lsb = (const float*)d_in[24];
  const float* ldg = (const float*)d_in[25];  const float* ldb = (const float*)d_in[26];
  const float* fw1 = (const float*)d_in[27];  const float* fbg = (const float*)d_in[28];
  const float* fbb = (const float*)d_in[29];  const float* fbm = (const float*)d_in[30];
  const float* fbv = (const float*)d_in[31];  const float* fw2 = (const float*)d_in[32];
  const float* fb2 = (const float*)d_in[33];

  char* ws = (char*)d_ws;
  __bf16*   fanT = (__bf16*)(ws + OFF_FANT);
  __bf16*   fbT  = (__bf16*)(ws + OFF_FBT);
  __bf16*   qpk  = (__bf16*)(ws + OFF_QPK);
  __bf16*   kpk  = (__bf16*)(ws + OFF_KPK);
  _Float16* vph  = (_Float16*)(ws + OFF_VPK);
  __bf16*   qdT  = (__bf16*)(ws + OFF_QDT);
  __bf16*   kdT  = (__bf16*)(ws + OFF_KDT);
  float*    qq   = (float*)(ws + OFF_QQ);
  float*    kk   = (float*)(ws + OFF_KK);
  unsigned int* fsd = (unsigned int*)(ws + OFF_FSD);
  _Float16* partO = (_Float16*)(ws + OFF_PART);
  float*    statM = (float*)(ws + OFF_STATM);
  float*    statL = (float*)(ws + OFF_STATL);
  __bf16*   csLN  = (__bf16*)(ws + OFF_CSLN);
  __bf16*   cdLN  = (__bf16*)(ws + OFF_CDLN);
  __bf16*   X1T   = (__bf16*)(ws + OFF_X1T);
  float*    out   = (float*)d_out;

  prep_kernel<<<dim3(192, B_), 256, 0, stream>>>(featA, featB, fanT, fbT, ling, linb);
  proj_mfma<<<dim3(N_ / 64, C_ / 64, 5 * B_), 256, 0, stream>>>(
      fanT, fbT, fanT, qw, qb, kw, kb, vw, vb, qdw, qdb, kdw, kdb);
  norms_b<<<dim3(N_ / 64, B_), 256, 0, stream>>>(qdT, kdT, qq, kk);
  pairdist_mfma<<<dim3(N_ / 64, N_ / 64, B_), 256, 0, stream>>>(
      qdT, kdT, qq, kk, xyzA, xyzB, fsd);
  dual_attn8<<<dim3(N_ / 64, H_ / 2, B_ * 2), 256, 0, stream>>>(
      qpk, kpk, vph, fsd, sbw1, sbg, sbb, sbm, sbv, sbw2, sbb2,
      partO, statM, statL);
  combine_ln<<<dim3(B_ * N_ / 4, 2), 256, 0, stream>>>(
      partO, statM, statL, csLN, cdLN, lsg, lsb, ldg, ldb);
  fusion1_mfma<<<dim3(N_ / 64, (2 * C_) / 64, B_), 256, 0, stream>>>(
      fanT, csLN, cdLN, X1T, fw1, fbg, fbb, fbm, fbv);
  fusion2_mfma<<<dim3(N_ / 64, C_ / 64, B_), 256, 0, stream>>>(
      X1T, fw2, fb2, featA, out);
}